// Round 10
// baseline (804.793 us; speedup 1.0000x reference)
//
#include <hip/hip_runtime.h>

// Peeling propagation on bipartite graph. V=1e6, F=4.2e6, K=3 (edge e -> function e/3).
// T=5. Output: deg (V floats) in d_out.
//
// R10: R9 CSR/frontier path with ONE fix — kc_csr was 300us / 1.0GB HBM traffic from
// write-allocate thrash (60 concurrent ~206KB scatter windows per XCD vs 4MB L2;
// lines evicted partially-dirty and refetched ~3.4x). kc_csr is now a persistent
// grid of 96 blocks looping over chunks -> ~12 windows/XCD (~2.5MB), L2-resident.
// Fallback path: R8 verbatim (used only if ws_size too small).

static constexpr int Vn = 1000000;
static constexpr int Fn = 4200000;
static constexpr int En = 3 * Fn;                          // 12.6M edges
static constexpr int Tn = 5;

static constexpr int SBLK = 2048;                          // sort blocks / regions
static constexpr int FPB  = 2052;                          // functions/block (mult of 4)
static constexpr int BIN_BITS = 10;                        // fine bin = 1024 vars
static constexpr int BIN_SIZE = 1 << BIN_BITS;
static constexpr int NB  = (Vn + BIN_SIZE - 1) >> BIN_BITS;   // 977 fine bins
static constexpr int NBP = 1024;
static constexpr int CH_BITS = 12;                         // chunk = 4096 vars
static constexpr int CH_SIZE = 1 << CH_BITS;
static constexpr int NCH = (Vn + CH_SIZE - 1) >> CH_BITS;  // 245 chunks
static constexpr int RCAP = 3 * FPB;
static constexpr int RSTRIDE = (RCAP + 63) & ~63;          // 6208
static constexpr int OROW = 1024;
static constexpr int AVW = NCH * (CH_SIZE / 64);           // R8 mask words
static constexpr unsigned int TCAP = 8u * 1024u * 1024u;   // touched-list capacity
static constexpr int FWORDS = Fn / 32;                     // 131250 fmask words
static constexpr int CSR_BLOCKS = 96;                      // persistent csr grid

// ======================= shared: transpose =======================
__global__ __launch_bounds__(256) void k_transpose(const unsigned short* __restrict__ in,
                                                   unsigned short* __restrict__ out) {
    __shared__ unsigned short t[64][65];
    const int bx = blockIdx.x, by = blockIdx.y;
    for (int i = threadIdx.x; i < 64 * 64; i += 256) {
        int r = i >> 6, c = i & 63;
        t[r][c] = in[(size_t)(by * 64 + r) * OROW + (bx * 64 + c)];
    }
    __syncthreads();
    for (int i = threadIdx.x; i < 64 * 64; i += 256) {
        int r = i >> 6, c = i & 63;
        out[(size_t)(bx * 64 + r) * SBLK + (by * 64 + c)] = t[c][r];
    }
}

// ======================= CSR-path kernels =======================

__global__ void kc_zero1(unsigned int* __restrict__ fep, unsigned int* __restrict__ counters) {
    int v = blockIdx.x * blockDim.x + threadIdx.x;
    if (v < Vn) fep[v] = 0u;
    if (v < 64) counters[v] = 0u;
}

__global__ void kc_fmask(const float* __restrict__ afunc, unsigned int* __restrict__ fmask) {
    int f = blockIdx.x * blockDim.x + threadIdx.x;
    bool act = (f < Fn) && (afunc[f] != 0.0f);
    unsigned long long b = __ballot(act);
    int lane = threadIdx.x & 63;
    if (f < Fn) {
        int w = f >> 5;
        if (lane == 0)  fmask[w] = (unsigned int)b;
        if (lane == 32) fmask[w] = (unsigned int)(b >> 32);
    }
}

// pack + hist + scan + scatter (u32 entries with fid_rel); gpack = staging (aliased into csr buf)
__global__ __launch_bounds__(256) void kc_pack_sort(
    const int* __restrict__ vidx, const float* __restrict__ ef,
    const float* __restrict__ afunc,
    unsigned long long* __restrict__ gpack,
    unsigned short* __restrict__ offs,
    unsigned int* __restrict__ sorted)          // [SBLK][RSTRIDE] u32 entries
{
    __shared__ unsigned int hist[NBP];
    __shared__ unsigned int cur[NBP];
    __shared__ unsigned int wsum[4];

    const int k = blockIdx.x;
    const int f0 = k * FPB;
    int n = Fn - f0; if (n < 0) n = 0; if (n > FPB) n = FPB;
    const int n4 = n >> 2;

    for (int i = threadIdx.x; i < NBP; i += 256) hist[i] = 0u;
    __syncthreads();

    for (int j = threadIdx.x; j < n4; j += 256) {
        const int fb = f0 + 4 * j, e = 3 * fb;
        int4 va = *(const int4*)(vidx + e);
        int4 vb = *(const int4*)(vidx + e + 4);
        int4 vc = *(const int4*)(vidx + e + 8);
        float4 ea = *(const float4*)(ef + e);
        float4 eb = *(const float4*)(ef + e + 4);
        float4 ec = *(const float4*)(ef + e + 8);
        float4 a4 = *(const float4*)(afunc + fb);
        int   vv[12] = {va.x, va.y, va.z, va.w, vb.x, vb.y, vb.z, vb.w, vc.x, vc.y, vc.z, vc.w};
        float ss[12] = {ea.x, ea.y, ea.z, ea.w, eb.x, eb.y, eb.z, eb.w, ec.x, ec.y, ec.z, ec.w};
        float aa[4]  = {a4.x, a4.y, a4.z, a4.w};
        unsigned long long gq[4];
        #pragma unroll
        for (int q = 0; q < 4; ++q) {
            int v0 = vv[3 * q], v1 = vv[3 * q + 1], v2 = vv[3 * q + 2];
            unsigned int s0 = ss[3 * q]     > 0.0f ? 1u : 0u;
            unsigned int s1 = ss[3 * q + 1] > 0.0f ? 1u : 0u;
            unsigned int s2 = ss[3 * q + 2] > 0.0f ? 1u : 0u;
            unsigned int act = aa[q] != 0.0f ? 1u : 0u;
            gq[q] = (unsigned long long)(unsigned int)v0
                  | ((unsigned long long)(unsigned int)v1 << 20)
                  | ((unsigned long long)(unsigned int)v2 << 40)
                  | ((unsigned long long)s0 << 60)
                  | ((unsigned long long)s1 << 61)
                  | ((unsigned long long)s2 << 62)
                  | ((unsigned long long)act << 63);
            if (act) {
                atomicAdd(&hist[v0 >> BIN_BITS], 1u);
                atomicAdd(&hist[v1 >> BIN_BITS], 1u);
                atomicAdd(&hist[v2 >> BIN_BITS], 1u);
            }
        }
        *(ulonglong2*)(gpack + fb)     = make_ulonglong2(gq[0], gq[1]);
        *(ulonglong2*)(gpack + fb + 2) = make_ulonglong2(gq[2], gq[3]);
    }
    for (int i = 4 * n4 + threadIdx.x; i < n; i += 256) {
        const int f = f0 + i, e0 = 3 * f;
        int v0 = vidx[e0], v1 = vidx[e0 + 1], v2 = vidx[e0 + 2];
        unsigned int s0 = ef[e0]     > 0.0f ? 1u : 0u;
        unsigned int s1 = ef[e0 + 1] > 0.0f ? 1u : 0u;
        unsigned int s2 = ef[e0 + 2] > 0.0f ? 1u : 0u;
        unsigned int act = afunc[f] != 0.0f ? 1u : 0u;
        unsigned long long g = (unsigned long long)(unsigned int)v0
                             | ((unsigned long long)(unsigned int)v1 << 20)
                             | ((unsigned long long)(unsigned int)v2 << 40)
                             | ((unsigned long long)s0 << 60)
                             | ((unsigned long long)s1 << 61)
                             | ((unsigned long long)s2 << 62)
                             | ((unsigned long long)act << 63);
        gpack[f] = g;
        if (act) {
            atomicAdd(&hist[v0 >> BIN_BITS], 1u);
            atomicAdd(&hist[v1 >> BIN_BITS], 1u);
            atomicAdd(&hist[v2 >> BIN_BITS], 1u);
        }
    }
    __syncthreads();

    {
        const int t = threadIdx.x, lane = t & 63, wid = t >> 6;
        unsigned int a0 = hist[4 * t], a1 = hist[4 * t + 1];
        unsigned int a2 = hist[4 * t + 2], a3 = hist[4 * t + 3];
        unsigned int tsum = a0 + a1 + a2 + a3;
        unsigned int x = tsum;
        #pragma unroll
        for (int off = 1; off < 64; off <<= 1) {
            unsigned int y = (unsigned int)__shfl_up((int)x, off);
            if (lane >= off) x += y;
        }
        if (lane == 63) wsum[wid] = x;
        __syncthreads();
        unsigned int wbase = 0;
        for (int w = 0; w < wid; ++w) wbase += wsum[w];
        unsigned int e0x = wbase + x - tsum;
        unsigned int e1x = e0x + a0, e2x = e1x + a1, e3x = e2x + a2;
        cur[4 * t] = e0x; cur[4 * t + 1] = e1x; cur[4 * t + 2] = e2x; cur[4 * t + 3] = e3x;
        unsigned short* row = offs + (size_t)k * OROW;
        if (4 * t     <= NB) row[4 * t]     = (unsigned short)e0x;
        if (4 * t + 1 <= NB) row[4 * t + 1] = (unsigned short)e1x;
        if (4 * t + 2 <= NB) row[4 * t + 2] = (unsigned short)e2x;
        if (4 * t + 3 <= NB) row[4 * t + 3] = (unsigned short)e3x;
    }
    __syncthreads();

    // pass 2: scatter u32 entries: v_local12 | sign<<12 | fid_rel<<13
    const size_t rbase = (size_t)k * RSTRIDE;
    for (int j = threadIdx.x; j < n4; j += 256) {
        const int fb = f0 + 4 * j;
        ulonglong2 ga = *(const ulonglong2*)(gpack + fb);
        ulonglong2 gb = *(const ulonglong2*)(gpack + fb + 2);
        unsigned long long gq[4] = {ga.x, ga.y, gb.x, gb.y};
        #pragma unroll
        for (int q = 0; q < 4; ++q) {
            unsigned long long g = gq[q];
            if ((long long)g < 0) {
                unsigned int fr = (unsigned int)(4 * j + q) << 13;
                unsigned int v0 = (unsigned int)(g & 0xFFFFFu);
                unsigned int v1 = (unsigned int)((g >> 20) & 0xFFFFFu);
                unsigned int v2 = (unsigned int)((g >> 40) & 0xFFFFFu);
                unsigned int sl0 = atomicAdd(&cur[v0 >> BIN_BITS], 1u);
                sorted[rbase + sl0] = (v0 & (CH_SIZE - 1)) | ((unsigned int)((g >> 60) & 1u) << 12) | fr;
                unsigned int sl1 = atomicAdd(&cur[v1 >> BIN_BITS], 1u);
                sorted[rbase + sl1] = (v1 & (CH_SIZE - 1)) | ((unsigned int)((g >> 61) & 1u) << 12) | fr;
                unsigned int sl2 = atomicAdd(&cur[v2 >> BIN_BITS], 1u);
                sorted[rbase + sl2] = (v2 & (CH_SIZE - 1)) | ((unsigned int)((g >> 62) & 1u) << 12) | fr;
            }
        }
    }
    for (int i = 4 * n4 + threadIdx.x; i < n; i += 256) {
        unsigned long long g = gpack[f0 + i];
        if ((long long)g < 0) {
            unsigned int fr = (unsigned int)i << 13;
            unsigned int v0 = (unsigned int)(g & 0xFFFFFu);
            unsigned int v1 = (unsigned int)((g >> 20) & 0xFFFFFu);
            unsigned int v2 = (unsigned int)((g >> 40) & 0xFFFFFu);
            unsigned int sl0 = atomicAdd(&cur[v0 >> BIN_BITS], 1u);
            sorted[rbase + sl0] = (v0 & (CH_SIZE - 1)) | ((unsigned int)((g >> 60) & 1u) << 12) | fr;
            unsigned int sl1 = atomicAdd(&cur[v1 >> BIN_BITS], 1u);
            sorted[rbase + sl1] = (v1 & (CH_SIZE - 1)) | ((unsigned int)((g >> 61) & 1u) << 12) | fr;
            unsigned int sl2 = atomicAdd(&cur[v2 >> BIN_BITS], 1u);
            sorted[rbase + sl2] = (v2 & (CH_SIZE - 1)) | ((unsigned int)((g >> 62) & 1u) << 12) | fr;
        }
    }
}

// per-chunk accumulate: packed, av8, cnt8, frontier0, fep=1, chunk totals
__global__ __launch_bounds__(1024) void kc_accum(
    const unsigned short* __restrict__ offs_T,
    const unsigned int* __restrict__ sorted,
    const float* __restrict__ avars,
    unsigned int* __restrict__ packed,
    unsigned char* __restrict__ av8,
    unsigned char* __restrict__ cnt8,
    unsigned int* __restrict__ frontA,
    unsigned int* __restrict__ counters,
    unsigned int* __restrict__ fep,
    unsigned int* __restrict__ chunk_total)
{
    __shared__ unsigned int acc[CH_SIZE];
    __shared__ unsigned short row0[SBLK];
    __shared__ unsigned short row1[SBLK];
    __shared__ unsigned int wred[16];
    const int c = blockIdx.x;
    const int r0 = 4 * c;
    const int r1 = (4 * c + 4 < NB) ? (4 * c + 4) : NB;
    for (int i = threadIdx.x; i < CH_SIZE; i += 1024) acc[i] = 0u;
    for (int i = threadIdx.x; i < SBLK; i += 1024) {
        row0[i] = offs_T[(size_t)r0 * SBLK + i];
        row1[i] = offs_T[(size_t)r1 * SBLK + i];
    }
    __syncthreads();
    for (int k = threadIdx.x; k < SBLK; k += 1024) {
        const int s0 = row0[k], s1 = row1[k];
        const unsigned int* seg = sorted + (size_t)k * RSTRIDE;
        for (int e = s0; e < s1; ++e) {
            unsigned int p = seg[e];
            atomicAdd(&acc[p & (CH_SIZE - 1)], 0x10000u | ((p >> 12) & 1u));
        }
    }
    __syncthreads();
    const int vbase = c << CH_BITS;
    unsigned int mysum = 0u;
    for (int i = threadIdx.x; i < CH_SIZE; i += 1024) {
        int v = vbase + i;
        bool valid = v < Vn;
        unsigned int p = valid ? acc[i] : 0u;
        unsigned int cnt = p >> 16, pos = p & 0xFFFFu;
        mysum += cnt;
        bool av = valid && (avars[v] != 0.0f);
        packed[vbase + i] = p;
        av8[vbase + i] = av ? 1 : 0;
        cnt8[vbase + i] = (unsigned char)(cnt > 255u ? 255u : cnt);
        if (av && (pos == 0u || pos == cnt)) {
            unsigned int ix = atomicAdd(&counters[0], 1u);
            frontA[ix] = (unsigned int)v;
            fep[v] = 1u;
        }
    }
    // block reduce mysum -> chunk_total[c]
    int lane = threadIdx.x & 63, wid = threadIdx.x >> 6;
    #pragma unroll
    for (int o = 32; o > 0; o >>= 1) mysum += (unsigned int)__shfl_down((int)mysum, o);
    if (lane == 0) wred[wid] = mysum;
    __syncthreads();
    if (threadIdx.x == 0) {
        unsigned int s = 0;
        for (int w = 0; w < 16; ++w) s += wred[w];
        chunk_total[c] = s;
    }
}

__global__ void kc_chunkscan(const unsigned int* __restrict__ chunk_total,
                             unsigned int* __restrict__ chunk_base) {
    __shared__ unsigned int s[256];
    int i = threadIdx.x;
    unsigned int own = (i < NCH) ? chunk_total[i] : 0u;
    s[i] = own;
    __syncthreads();
    for (int off = 1; off < 256; off <<= 1) {
        unsigned int add = (i >= off) ? s[i - off] : 0u;
        __syncthreads();
        s[i] += add;
        __syncthreads();
    }
    if (i < NCH) chunk_base[i] = s[i] - own;   // exclusive
}

// per-chunk CSR build. PERSISTENT grid (CSR_BLOCKS blocks loop over chunks):
// caps concurrent scatter windows per XCD so csr write lines stay L2-resident
// (fix for R9's 1.0GB write-allocate thrash).
__global__ __launch_bounds__(1024) void kc_csr(
    const unsigned short* __restrict__ offs_T,
    const unsigned int* __restrict__ sorted,
    const unsigned char* __restrict__ cnt8,
    const unsigned int* __restrict__ chunk_base,
    unsigned int* __restrict__ row_start,
    unsigned int* __restrict__ csr)
{
    __shared__ unsigned int cursor[CH_SIZE];
    __shared__ unsigned short row0[SBLK];
    __shared__ unsigned short row1[SBLK];
    __shared__ unsigned int wsum[16];
    for (int c = blockIdx.x; c < NCH; c += gridDim.x) {
        __syncthreads();                         // protect LDS reuse across chunk iterations
        const int vb = c << CH_BITS;
        const int r0 = 4 * c;
        const int r1 = (4 * c + 4 < NB) ? (4 * c + 4) : NB;
        for (int i = threadIdx.x; i < SBLK; i += 1024) {
            row0[i] = offs_T[(size_t)r0 * SBLK + i];
            row1[i] = offs_T[(size_t)r1 * SBLK + i];
        }
        // scan 4096 counts (4 per thread)
        {
            const int t = threadIdx.x, lane = t & 63, wid = t >> 6;
            uchar4 cc = *(const uchar4*)(cnt8 + vb + 4 * t);
            unsigned int c0 = cc.x, c1 = cc.y, c2 = cc.z, c3 = cc.w;
            unsigned int tsum = c0 + c1 + c2 + c3;
            unsigned int x = tsum;
            #pragma unroll
            for (int off = 1; off < 64; off <<= 1) {
                unsigned int y = (unsigned int)__shfl_up((int)x, off);
                if (lane >= off) x += y;
            }
            if (lane == 63) wsum[wid] = x;
            __syncthreads();
            unsigned int wbase = chunk_base[c];
            for (int w = 0; w < wid; ++w) wbase += wsum[w];
            unsigned int e0 = wbase + x - tsum;
            cursor[4 * t]     = e0;
            cursor[4 * t + 1] = e0 + c0;
            cursor[4 * t + 2] = e0 + c0 + c1;
            cursor[4 * t + 3] = e0 + c0 + c1 + c2;
            *(uint4*)(row_start + vb + 4 * t) = make_uint4(cursor[4*t], cursor[4*t+1], cursor[4*t+2], cursor[4*t+3]);
        }
        __syncthreads();
        for (int k = threadIdx.x; k < SBLK; k += 1024) {
            const int s0 = row0[k], s1 = row1[k];
            const unsigned int* seg = sorted + (size_t)k * RSTRIDE;
            const unsigned int fbase = (unsigned int)(k * FPB);
            for (int e = s0; e < s1; ++e) {
                unsigned int p = seg[e];
                unsigned int slot = atomicAdd(&cursor[p & (CH_SIZE - 1)], 1u);
                csr[slot] = ((fbase + (p >> 13)) << 1) | ((p >> 12) & 1u);
            }
        }
    }
}

__global__ void kc_zero2(unsigned int* __restrict__ tmp, unsigned int* __restrict__ eclaim) {
    int v = blockIdx.x * blockDim.x + threadIdx.x;
    if (v < Vn) { tmp[v] = 0u; eclaim[v] = 0u; }
}

// frontier walk: claim adjacent active functions, push decrements + touched
__global__ void kc_funcs(const unsigned int* __restrict__ csr,
                         const unsigned int* __restrict__ row_start,
                         const unsigned char* __restrict__ cnt8,
                         unsigned int* __restrict__ fmask,
                         const int* __restrict__ vidx, const float* __restrict__ ef,
                         unsigned int* __restrict__ tmp,
                         unsigned int* __restrict__ touched,
                         unsigned int* __restrict__ counters,
                         const unsigned int* __restrict__ frontier, int t)
{
    const int gid = blockIdx.x * blockDim.x + threadIdx.x;
    const int gsz = gridDim.x * blockDim.x;
    const unsigned int fcnt = counters[t];
    for (unsigned int i = gid; i < fcnt; i += gsz) {
        unsigned int v = frontier[i];
        unsigned int rs = row_start[v];
        unsigned int re = rs + cnt8[v];
        for (unsigned int j = rs; j < re; ++j) {
            unsigned int e = csr[j];
            unsigned int f = e >> 1;
            unsigned int w = f >> 5, m = 1u << (f & 31u);
            unsigned int old = atomicAnd(&fmask[w], ~m);
            if (old & m) {
                int e0 = 3 * (int)f;
                int a0 = vidx[e0], a1 = vidx[e0 + 1], a2 = vidx[e0 + 2];
                unsigned int s0 = ef[e0]     > 0.0f ? 1u : 0u;
                unsigned int s1 = ef[e0 + 1] > 0.0f ? 1u : 0u;
                unsigned int s2 = ef[e0 + 2] > 0.0f ? 1u : 0u;
                atomicAdd(&tmp[a0], 0x10000u | s0);
                atomicAdd(&tmp[a1], 0x10000u | s1);
                atomicAdd(&tmp[a2], 0x10000u | s2);
                unsigned int b = atomicAdd(&counters[8 + t], 3u);
                if (b + 3u <= TCAP) {
                    touched[b] = (unsigned int)a0;
                    touched[b + 1] = (unsigned int)a1;
                    touched[b + 2] = (unsigned int)a2;
                }
            }
        }
    }
}

// sparse update over (frontier ∪ touched), epoch-deduped; appends next frontier
__global__ void kc_update(unsigned int* __restrict__ packed,
                          unsigned int* __restrict__ tmp,
                          unsigned char* __restrict__ av8,
                          unsigned int* __restrict__ fep,
                          unsigned int* __restrict__ eclaim,
                          const unsigned int* __restrict__ touched,
                          const unsigned int* __restrict__ frontier_cur,
                          unsigned int* __restrict__ frontier_next,
                          unsigned int* __restrict__ counters, int t)
{
    const int gid = blockIdx.x * blockDim.x + threadIdx.x;
    const int gsz = gridDim.x * blockDim.x;
    const unsigned int fcnt = counters[t];
    unsigned int tc = counters[8 + t];
    const unsigned int tcnt = tc > TCAP ? TCAP : tc;
    const unsigned int total = fcnt + tcnt;
    const unsigned int epoch = (unsigned int)(t + 1);
    for (unsigned int i = gid; i < total; i += gsz) {
        unsigned int v = (i < fcnt) ? frontier_cur[i] : touched[i - fcnt];
        if (atomicExch(&eclaim[v], epoch) == epoch) continue;   // already processed this iter
        bool in_f = (fep[v] == epoch);
        bool av_old = in_f || (av8[v] != 0);
        unsigned int tp = tmp[v];
        unsigned int p = packed[v];
        if (tp != 0u) {
            if (av_old) { p -= tp; packed[v] = p; }
            tmp[v] = 0u;
        }
        if (in_f) av8[v] = 0;
        bool av_new = av_old && !in_f;
        if (av_new) {
            unsigned int cnt = p >> 16, pos = p & 0xFFFFu;
            if (pos == 0u || pos == cnt) {
                unsigned int ix = atomicAdd(&counters[t + 1], 1u);
                frontier_next[ix] = v;
                fep[v] = epoch + 1u;
            }
        }
    }
}

__global__ void kc_out(const unsigned int* __restrict__ packed, float* __restrict__ deg) {
    int v = blockIdx.x * blockDim.x + threadIdx.x;
    if (v < Vn) deg[v] = (float)(packed[v] >> 16);
}

// ======================= R8 fallback kernels (verbatim) =======================

__global__ __launch_bounds__(256) void k_pack_sort(
    const int* __restrict__ vidx, const float* __restrict__ ef,
    const float* __restrict__ afunc,
    unsigned long long* __restrict__ gpack,
    unsigned short* __restrict__ offs,
    unsigned short* __restrict__ sorted)
{
    __shared__ unsigned int hist[NBP];
    __shared__ unsigned int cur[NBP];
    __shared__ unsigned int wsum[4];

    const int k = blockIdx.x;
    const int f0 = k * FPB;
    int n = Fn - f0; if (n < 0) n = 0; if (n > FPB) n = FPB;
    const int n4 = n >> 2;

    for (int i = threadIdx.x; i < NBP; i += 256) hist[i] = 0u;
    __syncthreads();

    for (int j = threadIdx.x; j < n4; j += 256) {
        const int fb = f0 + 4 * j, e = 3 * fb;
        int4 va = *(const int4*)(vidx + e);
        int4 vb = *(const int4*)(vidx + e + 4);
        int4 vc = *(const int4*)(vidx + e + 8);
        float4 ea = *(const float4*)(ef + e);
        float4 eb = *(const float4*)(ef + e + 4);
        float4 ec = *(const float4*)(ef + e + 8);
        float4 a4 = *(const float4*)(afunc + fb);
        int   vv[12] = {va.x, va.y, va.z, va.w, vb.x, vb.y, vb.z, vb.w, vc.x, vc.y, vc.z, vc.w};
        float ss[12] = {ea.x, ea.y, ea.z, ea.w, eb.x, eb.y, eb.z, eb.w, ec.x, ec.y, ec.z, ec.w};
        float aa[4]  = {a4.x, a4.y, a4.z, a4.w};
        unsigned long long gq[4];
        #pragma unroll
        for (int q = 0; q < 4; ++q) {
            int v0 = vv[3 * q], v1 = vv[3 * q + 1], v2 = vv[3 * q + 2];
            unsigned int s0 = ss[3 * q]     > 0.0f ? 1u : 0u;
            unsigned int s1 = ss[3 * q + 1] > 0.0f ? 1u : 0u;
            unsigned int s2 = ss[3 * q + 2] > 0.0f ? 1u : 0u;
            unsigned int act = aa[q] != 0.0f ? 1u : 0u;
            gq[q] = (unsigned long long)(unsigned int)v0
                  | ((unsigned long long)(unsigned int)v1 << 20)
                  | ((unsigned long long)(unsigned int)v2 << 40)
                  | ((unsigned long long)s0 << 60)
                  | ((unsigned long long)s1 << 61)
                  | ((unsigned long long)s2 << 62)
                  | ((unsigned long long)act << 63);
            if (act) {
                atomicAdd(&hist[v0 >> BIN_BITS], 1u);
                atomicAdd(&hist[v1 >> BIN_BITS], 1u);
                atomicAdd(&hist[v2 >> BIN_BITS], 1u);
            }
        }
        *(ulonglong2*)(gpack + fb)     = make_ulonglong2(gq[0], gq[1]);
        *(ulonglong2*)(gpack + fb + 2) = make_ulonglong2(gq[2], gq[3]);
    }
    for (int i = 4 * n4 + threadIdx.x; i < n; i += 256) {
        const int f = f0 + i, e0 = 3 * f;
        int v0 = vidx[e0], v1 = vidx[e0 + 1], v2 = vidx[e0 + 2];
        unsigned int s0 = ef[e0]     > 0.0f ? 1u : 0u;
        unsigned int s1 = ef[e0 + 1] > 0.0f ? 1u : 0u;
        unsigned int s2 = ef[e0 + 2] > 0.0f ? 1u : 0u;
        unsigned int act = afunc[f] != 0.0f ? 1u : 0u;
        unsigned long long g = (unsigned long long)(unsigned int)v0
                             | ((unsigned long long)(unsigned int)v1 << 20)
                             | ((unsigned long long)(unsigned int)v2 << 40)
                             | ((unsigned long long)s0 << 60)
                             | ((unsigned long long)s1 << 61)
                             | ((unsigned long long)s2 << 62)
                             | ((unsigned long long)act << 63);
        gpack[f] = g;
        if (act) {
            atomicAdd(&hist[v0 >> BIN_BITS], 1u);
            atomicAdd(&hist[v1 >> BIN_BITS], 1u);
            atomicAdd(&hist[v2 >> BIN_BITS], 1u);
        }
    }
    __syncthreads();

    {
        const int t = threadIdx.x, lane = t & 63, wid = t >> 6;
        unsigned int a0 = hist[4 * t], a1 = hist[4 * t + 1];
        unsigned int a2 = hist[4 * t + 2], a3 = hist[4 * t + 3];
        unsigned int tsum = a0 + a1 + a2 + a3;
        unsigned int x = tsum;
        #pragma unroll
        for (int off = 1; off < 64; off <<= 1) {
            unsigned int y = (unsigned int)__shfl_up((int)x, off);
            if (lane >= off) x += y;
        }
        if (lane == 63) wsum[wid] = x;
        __syncthreads();
        unsigned int wbase = 0;
        for (int w = 0; w < wid; ++w) wbase += wsum[w];
        unsigned int e0x = wbase + x - tsum;
        unsigned int e1x = e0x + a0, e2x = e1x + a1, e3x = e2x + a2;
        cur[4 * t] = e0x; cur[4 * t + 1] = e1x; cur[4 * t + 2] = e2x; cur[4 * t + 3] = e3x;
        unsigned short* row = offs + (size_t)k * OROW;
        if (4 * t     <= NB) row[4 * t]     = (unsigned short)e0x;
        if (4 * t + 1 <= NB) row[4 * t + 1] = (unsigned short)e1x;
        if (4 * t + 2 <= NB) row[4 * t + 2] = (unsigned short)e2x;
        if (4 * t + 3 <= NB) row[4 * t + 3] = (unsigned short)e3x;
    }
    __syncthreads();

    const size_t rbase = (size_t)k * RSTRIDE;
    for (int j = threadIdx.x; j < n4; j += 256) {
        const int fb = f0 + 4 * j;
        ulonglong2 ga = *(const ulonglong2*)(gpack + fb);
        ulonglong2 gb = *(const ulonglong2*)(gpack + fb + 2);
        unsigned long long gq[4] = {ga.x, ga.y, gb.x, gb.y};
        #pragma unroll
        for (int q = 0; q < 4; ++q) {
            unsigned long long g = gq[q];
            if ((long long)g < 0) {
                unsigned int v0 = (unsigned int)(g & 0xFFFFFu);
                unsigned int v1 = (unsigned int)((g >> 20) & 0xFFFFFu);
                unsigned int v2 = (unsigned int)((g >> 40) & 0xFFFFFu);
                unsigned int sl0 = atomicAdd(&cur[v0 >> BIN_BITS], 1u);
                sorted[rbase + sl0] = (unsigned short)((v0 & (CH_SIZE - 1)) | ((unsigned int)((g >> 60) & 1u) << CH_BITS));
                unsigned int sl1 = atomicAdd(&cur[v1 >> BIN_BITS], 1u);
                sorted[rbase + sl1] = (unsigned short)((v1 & (CH_SIZE - 1)) | ((unsigned int)((g >> 61) & 1u) << CH_BITS));
                unsigned int sl2 = atomicAdd(&cur[v2 >> BIN_BITS], 1u);
                sorted[rbase + sl2] = (unsigned short)((v2 & (CH_SIZE - 1)) | ((unsigned int)((g >> 62) & 1u) << CH_BITS));
            }
        }
    }
    for (int i = 4 * n4 + threadIdx.x; i < n; i += 256) {
        unsigned long long g = gpack[f0 + i];
        if ((long long)g < 0) {
            unsigned int v0 = (unsigned int)(g & 0xFFFFFu);
            unsigned int v1 = (unsigned int)((g >> 20) & 0xFFFFFu);
            unsigned int v2 = (unsigned int)((g >> 40) & 0xFFFFFu);
            unsigned int sl0 = atomicAdd(&cur[v0 >> BIN_BITS], 1u);
            sorted[rbase + sl0] = (unsigned short)((v0 & (CH_SIZE - 1)) | ((unsigned int)((g >> 60) & 1u) << CH_BITS));
            unsigned int sl1 = atomicAdd(&cur[v1 >> BIN_BITS], 1u);
            sorted[rbase + sl1] = (unsigned short)((v1 & (CH_SIZE - 1)) | ((unsigned int)((g >> 61) & 1u) << CH_BITS));
            unsigned int sl2 = atomicAdd(&cur[v2 >> BIN_BITS], 1u);
            sorted[rbase + sl2] = (unsigned short)((v2 & (CH_SIZE - 1)) | ((unsigned int)((g >> 62) & 1u) << CH_BITS));
        }
    }
}

__global__ __launch_bounds__(1024) void k_accum(
    const unsigned short* __restrict__ offs_T,
    const unsigned short* __restrict__ sorted,
    const float* __restrict__ avars,
    unsigned int* __restrict__ packed,
    unsigned long long* __restrict__ avm,
    unsigned long long* __restrict__ svm,
    unsigned char* __restrict__ sgrp)
{
    __shared__ unsigned int acc[CH_SIZE];
    __shared__ unsigned short row0[SBLK];
    __shared__ unsigned short row1[SBLK];
    const int c = blockIdx.x;
    const int r0 = 4 * c;
    const int r1 = (4 * c + 4 < NB) ? (4 * c + 4) : NB;
    for (int i = threadIdx.x; i < CH_SIZE; i += 1024) acc[i] = 0u;
    for (int i = threadIdx.x; i < SBLK; i += 1024) {
        row0[i] = offs_T[(size_t)r0 * SBLK + i];
        row1[i] = offs_T[(size_t)r1 * SBLK + i];
    }
    __syncthreads();
    for (int k = threadIdx.x; k < SBLK; k += 1024) {
        const int s0 = row0[k], s1 = row1[k];
        const unsigned short* seg = sorted + (size_t)k * RSTRIDE;
        for (int e = s0; e < s1; ++e) {
            unsigned int p = seg[e];
            atomicAdd(&acc[p & (CH_SIZE - 1)], 0x10000u | (p >> CH_BITS));
        }
    }
    __syncthreads();
    const int vbase = c << CH_BITS;
    for (int i = threadIdx.x; i < CH_SIZE; i += 1024) {
        int v = vbase + i;
        bool valid = v < Vn;
        unsigned int p = valid ? acc[i] : 0u;
        bool av = valid && (avars[v] != 0.0f);
        unsigned int cnt = p >> 16, pos = p & 0xFFFFu;
        bool sv = av && (pos == 0u || pos == cnt);
        unsigned long long avb = __ballot(av);
        unsigned long long svb = __ballot(sv);
        if (valid) packed[v] = p;
        if ((threadIdx.x & 63) == 0) {
            avm[v >> 6] = avb;
            svm[v >> 6] = svb;
            sgrp[v >> 6] = (svb != 0ull) ? 1 : 0;
        }
    }
}

__global__ void k_zero_tmp(unsigned int* __restrict__ tmp, unsigned char* __restrict__ tgrp) {
    int v = blockIdx.x * blockDim.x + threadIdx.x;
    if (v < Vn) tmp[v] = 0u;
    if (v < AVW) tgrp[v] = 0;
}

__device__ __forceinline__ void fire_one(unsigned long long g, int f,
                                         unsigned long long* __restrict__ gpack,
                                         const unsigned int* __restrict__ svm32,
                                         const unsigned char* __restrict__ sgrp,
                                         unsigned int* __restrict__ tmp,
                                         unsigned char* __restrict__ tgrp)
{
    if ((long long)g >= 0) return;
    unsigned int v0 = (unsigned int)(g & 0xFFFFFu);
    unsigned int v1 = (unsigned int)((g >> 20) & 0xFFFFFu);
    unsigned int v2 = (unsigned int)((g >> 40) & 0xFFFFFu);
    if (!(sgrp[v0 >> 6] | sgrp[v1 >> 6] | sgrp[v2 >> 6])) return;
    unsigned int hit = ((svm32[v0 >> 5] >> (v0 & 31u)) |
                        (svm32[v1 >> 5] >> (v1 & 31u)) |
                        (svm32[v2 >> 5] >> (v2 & 31u))) & 1u;
    if (!hit) return;
    gpack[f] = g & ~(1ull << 63);
    atomicAdd(&tmp[v0], 0x10000u | (unsigned int)((g >> 60) & 1u));
    atomicAdd(&tmp[v1], 0x10000u | (unsigned int)((g >> 61) & 1u));
    atomicAdd(&tmp[v2], 0x10000u | (unsigned int)((g >> 62) & 1u));
    tgrp[v0 >> 6] = 1; tgrp[v1 >> 6] = 1; tgrp[v2 >> 6] = 1;
}

__global__ void k_funcs(unsigned long long* __restrict__ gpack,
                        const unsigned int* __restrict__ svm32,
                        const unsigned char* __restrict__ sgrp,
                        unsigned int* __restrict__ tmp,
                        unsigned char* __restrict__ tgrp)
{
    int gid = blockIdx.x * blockDim.x + threadIdx.x;
    int f = 2 * gid;
    if (f >= Fn) return;
    ulonglong2 g2 = *(const ulonglong2*)(gpack + f);
    fire_one(g2.x, f,     gpack, svm32, sgrp, tmp, tgrp);
    fire_one(g2.y, f + 1, gpack, svm32, sgrp, tmp, tgrp);
}

__global__ void k_update(unsigned int* __restrict__ packed,
                         unsigned int* __restrict__ tmp,
                         unsigned long long* __restrict__ avm,
                         unsigned long long* __restrict__ svm,
                         unsigned char* __restrict__ sgrp,
                         unsigned char* __restrict__ tgrp,
                         float* __restrict__ deg, int write_deg)
{
    int v = blockIdx.x * blockDim.x + threadIdx.x;
    int lane = threadIdx.x & 63;
    bool valid = v < Vn;
    unsigned long long avw = 0ull, svw = 0ull;
    unsigned char tg = 0;
    if (valid) {
        avw = avm[v >> 6]; svw = svm[v >> 6];
        tg = tgrp[v >> 6];
    }
    bool av_old = valid && ((avw >> lane) & 1ull);
    bool sv     = valid && ((svw >> lane) & 1ull);
    bool av_new = av_old && !sv;
    unsigned int p = 0u;
    if (valid) {
        p = packed[v];
        if (tg) {
            unsigned int tp = tmp[v];
            if (tp != 0u) {
                if (av_old) { p -= tp; packed[v] = p; }
                tmp[v] = 0u;
            }
        }
    }
    unsigned int c = p >> 16, pos = p & 0xFFFFu;
    bool nsv = av_new && (pos == 0u || pos == c);
    unsigned long long nsvb = __ballot(nsv);
    if (lane == 0 && valid) {
        svm[v >> 6] = nsvb;
        avm[v >> 6] = avw & ~svw;
        sgrp[v >> 6] = (nsvb != 0ull) ? 1 : 0;
        if (tg) tgrp[v >> 6] = 0;
    }
    if (write_deg && valid) deg[v] = (float)c;
}

// ======================= launcher =======================
extern "C" void kernel_launch(void* const* d_in, const int* in_sizes, int n_in,
                              void* d_out, int out_size, void* d_ws, size_t ws_size,
                              hipStream_t stream) {
    const int*   graph_map        = (const int*)d_in[0];
    const float* edge_feature     = (const float*)d_in[1];
    const float* active_variables = (const float*)d_in[2];
    const float* active_functions = (const float*)d_in[3];
    const int* vidx = graph_map;
    float* deg = (float*)d_out;
    char* ws = (char*)d_ws;

    const int BS = 256;
    const int gV = (Vn + BS - 1) / BS;

    // ---- CSR-path workspace requirement ----
    const size_t szA   = 4ull * SBLK * RSTRIDE;       // u32 regions (alias: frontB/tmp/eclaim/touched)
    const size_t szB   = 2ull * 2ull * SBLK * OROW;   // offs + offs_T
    const size_t szC   = 4ull * NCH * CH_SIZE;        // packed (padded)
    const size_t szD   = 4ull * En;                   // csr (gpack staging aliases here)
    const size_t szE   = 4ull * NCH * CH_SIZE;        // row_start
    const size_t szF   = 1ull * NCH * CH_SIZE;        // cnt8
    const size_t szFep = 4ull * Vn;
    const size_t szAv8 = 1ull * NCH * CH_SIZE;
    const size_t szFrA = 4ull * Vn;
    const size_t szFm  = 4ull * ((FWORDS + 127) & ~127);
    const size_t szMisc = 65536;                      // counters + chunk arrays + pad
    const size_t NEED = szA + szB + szC + szD + szE + szF + szFep + szAv8 + szFrA + szFm + szMisc;

    if (ws_size >= NEED) {
        // ================= CSR / frontier path =================
        size_t off = 0;
        unsigned int* regions32 = (unsigned int*)(ws + off); off += szA;
        // aliases inside regions32 (used only after kc_csr):
        unsigned int* frontB  = (unsigned int*)((char*)regions32);
        unsigned int* tmp     = (unsigned int*)((char*)regions32 + 4ull * Vn);
        unsigned int* eclaim  = (unsigned int*)((char*)regions32 + 8ull * Vn);
        unsigned int* touched = (unsigned int*)((char*)regions32 + 12ull * Vn);  // 4*TCAP = 33.5MB, fits
        unsigned short* offs   = (unsigned short*)(ws + off); off += 2ull * SBLK * OROW;
        unsigned short* offs_T = (unsigned short*)(ws + off); off += 2ull * SBLK * OROW;
        unsigned int* packed   = (unsigned int*)(ws + off); off += szC;
        unsigned int* csr      = (unsigned int*)(ws + off); off += szD;
        unsigned long long* gpack = (unsigned long long*)csr;   // staging, dead before kc_csr writes
        unsigned int* row_start = (unsigned int*)(ws + off); off += szE;
        unsigned char* cnt8     = (unsigned char*)(ws + off); off += szF;
        unsigned int* fep       = (unsigned int*)(ws + off); off += szFep;
        unsigned char* av8      = (unsigned char*)(ws + off); off += szAv8;
        unsigned int* frontA    = (unsigned int*)(ws + off); off += szFrA;
        unsigned int* fmask     = (unsigned int*)(ws + off); off += szFm;
        unsigned int* counters  = (unsigned int*)(ws + off); off += 1024;
        unsigned int* chunk_total = (unsigned int*)(ws + off); off += 1024;
        unsigned int* chunk_base  = (unsigned int*)(ws + off); off += 1024;

        kc_zero1<<<gV, BS, 0, stream>>>(fep, counters);
        kc_fmask<<<(Fn + BS - 1) / BS, BS, 0, stream>>>(active_functions, fmask);
        kc_pack_sort<<<SBLK, 256, 0, stream>>>(vidx, edge_feature, active_functions, gpack, offs, regions32);
        k_transpose<<<dim3(OROW / 64, SBLK / 64), 256, 0, stream>>>(offs, offs_T);
        kc_accum<<<NCH, 1024, 0, stream>>>(offs_T, regions32, active_variables, packed,
                                           av8, cnt8, frontA, counters, fep, chunk_total);
        kc_chunkscan<<<1, 256, 0, stream>>>(chunk_total, chunk_base);
        kc_csr<<<CSR_BLOCKS, 1024, 0, stream>>>(offs_T, regions32, cnt8, chunk_base, row_start, csr);
        kc_zero2<<<gV, BS, 0, stream>>>(tmp, eclaim);
        for (int t = 0; t < Tn; ++t) {
            const unsigned int* fcur = (t & 1) ? frontB : frontA;
            unsigned int* fnext = (t & 1) ? frontA : frontB;
            kc_funcs<<<256, 256, 0, stream>>>(csr, row_start, cnt8, fmask, vidx, edge_feature,
                                              tmp, touched, counters, fcur, t);
            kc_update<<<256, 256, 0, stream>>>(packed, tmp, av8, fep, eclaim, touched,
                                               fcur, fnext, counters, t);
        }
        kc_out<<<gV, BS, 0, stream>>>(packed, deg);
    } else {
        // ================= R8 fallback path =================
        size_t off = 0;
        unsigned long long* gpack = (unsigned long long*)(ws + off); off += 8ull * Fn;
        unsigned int* packed      = (unsigned int*)(ws + off);       off += 4ull * Vn;
        unsigned long long* avm   = (unsigned long long*)(ws + off); off += 8ull * AVW;
        unsigned long long* svm   = (unsigned long long*)(ws + off); off += 8ull * AVW;
        unsigned char* sgrp       = (unsigned char*)(ws + off);      off += (size_t)((AVW + 255) & ~255);
        unsigned char* tgrp       = (unsigned char*)(ws + off);      off += (size_t)((AVW + 255) & ~255);
        unsigned short* offs      = (unsigned short*)(ws + off);     off += 2ull * SBLK * OROW;
        unsigned short* offs_T    = (unsigned short*)(ws + off);     off += 2ull * SBLK * OROW;
        unsigned short* sorted    = (unsigned short*)(ws + off);     off += 2ull * SBLK * RSTRIDE;
        unsigned int* tmp = (unsigned int*)sorted;

        const int gF2 = (Fn / 2 + BS - 1) / BS;
        k_pack_sort<<<SBLK, 256, 0, stream>>>(vidx, edge_feature, active_functions, gpack, offs, sorted);
        k_transpose<<<dim3(OROW / 64, SBLK / 64), 256, 0, stream>>>(offs, offs_T);
        k_accum<<<NCH, 1024, 0, stream>>>(offs_T, sorted, active_variables, packed, avm, svm, sgrp);
        k_zero_tmp<<<gV, BS, 0, stream>>>(tmp, tgrp);
        for (int t = 0; t < Tn; ++t) {
            k_funcs<<<gF2, BS, 0, stream>>>(gpack, (const unsigned int*)svm, sgrp, tmp, tgrp);
            k_update<<<gV, BS, 0, stream>>>(packed, tmp, avm, svm, sgrp, tgrp, deg, (t == Tn - 1) ? 1 : 0);
        }
    }
}

// Round 11
// 617.365 us; speedup vs baseline: 1.3036x; 1.3036x over previous
//
#include <hip/hip_runtime.h>

// Peeling propagation on bipartite graph. V=1e6, F=4.2e6, K=3 (edge e -> function e/3).
// T=5. Output: deg (V floats) in d_out.
//
// R11 (CSR/frontier path, ws-gated; fallback = R8 verbatim):
//  * kc_csr2: LDS-staged per-bin CSR build. R10's global random scatter wrote 389MB
//    HBM for a 54MB payload (write-allocate, partial-line evictions). Now each fine
//    bin (1024 vars, ~52KB of entries) is scattered in LDS and written out as one
//    contiguous coalesced stream. 245 blocks x 16 waves.
//  * kc_pack_sort: records carried in REGISTERS across the scan (no gpack staging;
//    CSR path reads vidx/ef directly in the frontier walk).
//  * kc_funcs: av-gated atomicSub directly on packed -> no tmp array, no tmp zeroing,
//    simpler update; update_4 dead -> skipped. 15 launches total.

static constexpr int Vn = 1000000;
static constexpr int Fn = 4200000;
static constexpr int En = 3 * Fn;                          // 12.6M edges
static constexpr int Tn = 5;

static constexpr int SBLK = 2048;                          // sort blocks / regions
static constexpr int FPB  = 2052;                          // functions/block (mult of 4; SBLK*FPB >= Fn, all n%4==0)
static constexpr int BIN_BITS = 10;                        // fine bin = 1024 vars
static constexpr int BIN_SIZE = 1 << BIN_BITS;
static constexpr int NB  = (Vn + BIN_SIZE - 1) >> BIN_BITS;   // 977 fine bins
static constexpr int NBP = 1024;
static constexpr int CH_BITS = 12;                         // chunk = 4096 vars
static constexpr int CH_SIZE = 1 << CH_BITS;
static constexpr int NCH = (Vn + CH_SIZE - 1) >> CH_BITS;  // 245 chunks
static constexpr int RCAP = 3 * FPB;
static constexpr int RSTRIDE = (RCAP + 63) & ~63;          // 6208
static constexpr int OROW = 1024;
static constexpr int AVW = NCH * (CH_SIZE / 64);           // R8 mask words
static constexpr unsigned int TCAP = 8u * 1024u * 1024u;   // touched-list capacity
static constexpr int FWORDS = Fn / 32;                     // 131250 fmask words
static constexpr int STAGE_CAP = 14336;                    // LDS stage entries (bin expect ~12.9K, ~9 sigma margin)

// ======================= shared: transpose =======================
__global__ __launch_bounds__(256) void k_transpose(const unsigned short* __restrict__ in,
                                                   unsigned short* __restrict__ out) {
    __shared__ unsigned short t[64][65];
    const int bx = blockIdx.x, by = blockIdx.y;
    for (int i = threadIdx.x; i < 64 * 64; i += 256) {
        int r = i >> 6, c = i & 63;
        t[r][c] = in[(size_t)(by * 64 + r) * OROW + (bx * 64 + c)];
    }
    __syncthreads();
    for (int i = threadIdx.x; i < 64 * 64; i += 256) {
        int r = i >> 6, c = i & 63;
        out[(size_t)(bx * 64 + r) * SBLK + (by * 64 + c)] = t[c][r];
    }
}

// ======================= CSR-path kernels =======================

// fused init: fmask ballots + zero fep + zero counters
__global__ void kc_init(const float* __restrict__ afunc, unsigned int* __restrict__ fmask,
                        unsigned int* __restrict__ fep, unsigned int* __restrict__ counters) {
    int f = blockIdx.x * blockDim.x + threadIdx.x;
    bool act = (f < Fn) && (afunc[f] != 0.0f);
    unsigned long long b = __ballot(act);
    int lane = threadIdx.x & 63;
    if (f < Fn) {
        int w = f >> 5;
        if (lane == 0)  fmask[w] = (unsigned int)b;
        if (lane == 32) fmask[w] = (unsigned int)(b >> 32);
    }
    if (f < Vn) fep[f] = 0u;
    if (f < 64) counters[f] = 0u;
}

// pack+hist+scan+scatter with REGISTER carry (no gpack staging).
// sorted entry (u32): v_local12 | sign<<12 | fid_rel<<13
__global__ __launch_bounds__(256) void kc_pack_sort(
    const int* __restrict__ vidx, const float* __restrict__ ef,
    const float* __restrict__ afunc,
    unsigned short* __restrict__ offs,
    unsigned int* __restrict__ sorted)
{
    __shared__ unsigned int hist[NBP];
    __shared__ unsigned int cur[NBP];
    __shared__ unsigned int wsum[4];

    const int k = blockIdx.x;
    const int f0 = k * FPB;
    int n = Fn - f0; if (n < 0) n = 0; if (n > FPB) n = FPB;   // always %4==0
    const int n4 = n >> 2;

    for (int i = threadIdx.x; i < NBP; i += 256) hist[i] = 0u;
    __syncthreads();

    unsigned long long gsave[3][4];   // up to 3 loop iterations x 4 functions

    // pass 1: load once, build records in regs, histogram fine bins
    {
        int jj = 0;
        for (int j = threadIdx.x; j < n4; j += 256, ++jj) {
            const int fb = f0 + 4 * j, e = 3 * fb;
            int4 va = *(const int4*)(vidx + e);
            int4 vb = *(const int4*)(vidx + e + 4);
            int4 vc = *(const int4*)(vidx + e + 8);
            float4 ea = *(const float4*)(ef + e);
            float4 eb = *(const float4*)(ef + e + 4);
            float4 ec = *(const float4*)(ef + e + 8);
            float4 a4 = *(const float4*)(afunc + fb);
            int   vv[12] = {va.x, va.y, va.z, va.w, vb.x, vb.y, vb.z, vb.w, vc.x, vc.y, vc.z, vc.w};
            float ss[12] = {ea.x, ea.y, ea.z, ea.w, eb.x, eb.y, eb.z, eb.w, ec.x, ec.y, ec.z, ec.w};
            float aa[4]  = {a4.x, a4.y, a4.z, a4.w};
            #pragma unroll
            for (int q = 0; q < 4; ++q) {
                int v0 = vv[3 * q], v1 = vv[3 * q + 1], v2 = vv[3 * q + 2];
                unsigned int s0 = ss[3 * q]     > 0.0f ? 1u : 0u;
                unsigned int s1 = ss[3 * q + 1] > 0.0f ? 1u : 0u;
                unsigned int s2 = ss[3 * q + 2] > 0.0f ? 1u : 0u;
                unsigned int act = aa[q] != 0.0f ? 1u : 0u;
                gsave[jj][q] = (unsigned long long)(unsigned int)v0
                             | ((unsigned long long)(unsigned int)v1 << 20)
                             | ((unsigned long long)(unsigned int)v2 << 40)
                             | ((unsigned long long)s0 << 60)
                             | ((unsigned long long)s1 << 61)
                             | ((unsigned long long)s2 << 62)
                             | ((unsigned long long)act << 63);
                if (act) {
                    atomicAdd(&hist[v0 >> BIN_BITS], 1u);
                    atomicAdd(&hist[v1 >> BIN_BITS], 1u);
                    atomicAdd(&hist[v2 >> BIN_BITS], 1u);
                }
            }
        }
    }
    __syncthreads();

    // shuffle-based exclusive scan over 1024 fine bins
    {
        const int t = threadIdx.x, lane = t & 63, wid = t >> 6;
        unsigned int a0 = hist[4 * t], a1 = hist[4 * t + 1];
        unsigned int a2 = hist[4 * t + 2], a3 = hist[4 * t + 3];
        unsigned int tsum = a0 + a1 + a2 + a3;
        unsigned int x = tsum;
        #pragma unroll
        for (int off = 1; off < 64; off <<= 1) {
            unsigned int y = (unsigned int)__shfl_up((int)x, off);
            if (lane >= off) x += y;
        }
        if (lane == 63) wsum[wid] = x;
        __syncthreads();
        unsigned int wbase = 0;
        for (int w = 0; w < wid; ++w) wbase += wsum[w];
        unsigned int e0x = wbase + x - tsum;
        unsigned int e1x = e0x + a0, e2x = e1x + a1, e3x = e2x + a2;
        cur[4 * t] = e0x; cur[4 * t + 1] = e1x; cur[4 * t + 2] = e2x; cur[4 * t + 3] = e3x;
        unsigned short* row = offs + (size_t)k * OROW;
        if (4 * t     <= NB) row[4 * t]     = (unsigned short)e0x;
        if (4 * t + 1 <= NB) row[4 * t + 1] = (unsigned short)e1x;
        if (4 * t + 2 <= NB) row[4 * t + 2] = (unsigned short)e2x;
        if (4 * t + 3 <= NB) row[4 * t + 3] = (unsigned short)e3x;
    }
    __syncthreads();

    // pass 2: scatter from registers
    {
        const size_t rbase = (size_t)k * RSTRIDE;
        int jj = 0;
        for (int j = threadIdx.x; j < n4; j += 256, ++jj) {
            #pragma unroll
            for (int q = 0; q < 4; ++q) {
                unsigned long long g = gsave[jj][q];
                if ((long long)g < 0) {
                    unsigned int fr = (unsigned int)(4 * j + q) << 13;
                    unsigned int v0 = (unsigned int)(g & 0xFFFFFu);
                    unsigned int v1 = (unsigned int)((g >> 20) & 0xFFFFFu);
                    unsigned int v2 = (unsigned int)((g >> 40) & 0xFFFFFu);
                    unsigned int sl0 = atomicAdd(&cur[v0 >> BIN_BITS], 1u);
                    sorted[rbase + sl0] = (v0 & (CH_SIZE - 1)) | ((unsigned int)((g >> 60) & 1u) << 12) | fr;
                    unsigned int sl1 = atomicAdd(&cur[v1 >> BIN_BITS], 1u);
                    sorted[rbase + sl1] = (v1 & (CH_SIZE - 1)) | ((unsigned int)((g >> 61) & 1u) << 12) | fr;
                    unsigned int sl2 = atomicAdd(&cur[v2 >> BIN_BITS], 1u);
                    sorted[rbase + sl2] = (v2 & (CH_SIZE - 1)) | ((unsigned int)((g >> 62) & 1u) << 12) | fr;
                }
            }
        }
    }
}

// per-chunk accumulate: packed, av8, cnt8, frontier0, fep=1, per-fine-bin totals
__global__ __launch_bounds__(1024) void kc_accum(
    const unsigned short* __restrict__ offs_T,
    const unsigned int* __restrict__ sorted,
    const float* __restrict__ avars,
    unsigned int* __restrict__ packed,
    unsigned char* __restrict__ av8,
    unsigned char* __restrict__ cnt8,
    unsigned int* __restrict__ frontA,
    unsigned int* __restrict__ counters,
    unsigned int* __restrict__ fep,
    unsigned int* __restrict__ bin_total)
{
    __shared__ unsigned int acc[CH_SIZE];
    __shared__ unsigned short row0[SBLK];
    __shared__ unsigned short row1[SBLK];
    __shared__ unsigned int wred[16][4];
    const int c = blockIdx.x;
    const int r0 = 4 * c;
    const int r1 = (4 * c + 4 < NB) ? (4 * c + 4) : NB;
    for (int i = threadIdx.x; i < CH_SIZE; i += 1024) acc[i] = 0u;
    for (int i = threadIdx.x; i < SBLK; i += 1024) {
        row0[i] = offs_T[(size_t)r0 * SBLK + i];
        row1[i] = offs_T[(size_t)r1 * SBLK + i];
    }
    __syncthreads();
    for (int k = threadIdx.x; k < SBLK; k += 1024) {
        const int s0 = row0[k], s1 = row1[k];
        const unsigned int* seg = sorted + (size_t)k * RSTRIDE;
        for (int e = s0; e < s1; ++e) {
            unsigned int p = seg[e];
            atomicAdd(&acc[p & (CH_SIZE - 1)], 0x10000u | ((p >> 12) & 1u));
        }
    }
    __syncthreads();
    const int vbase = c << CH_BITS;
    unsigned int qs[4] = {0u, 0u, 0u, 0u};
    {
        int jq = 0;
        for (int i = threadIdx.x; i < CH_SIZE; i += 1024, ++jq) {   // jq indexes the fine bin (quarter)
            int v = vbase + i;
            bool valid = v < Vn;
            unsigned int p = valid ? acc[i] : 0u;
            unsigned int cnt = p >> 16, pos = p & 0xFFFFu;
            qs[jq] = cnt;
            bool av = valid && (avars[v] != 0.0f);
            packed[vbase + i] = p;
            av8[vbase + i] = av ? 1 : 0;
            cnt8[vbase + i] = (unsigned char)(cnt > 255u ? 255u : cnt);
            if (av && (pos == 0u || pos == cnt)) {
                unsigned int ix = atomicAdd(&counters[0], 1u);
                frontA[ix] = (unsigned int)v;
                fep[v] = 1u;
            }
        }
    }
    // 4 block reductions -> bin_total[4c + jq]
    int lane = threadIdx.x & 63, wid = threadIdx.x >> 6;
    #pragma unroll
    for (int jq = 0; jq < 4; ++jq) {
        unsigned int s = qs[jq];
        #pragma unroll
        for (int o = 32; o > 0; o >>= 1) s += (unsigned int)__shfl_down((int)s, o);
        if (lane == 0) wred[wid][jq] = s;
    }
    __syncthreads();
    if (threadIdx.x < 4) {
        unsigned int s = 0;
        for (int w = 0; w < 16; ++w) s += wred[w][threadIdx.x];
        bin_total[4 * c + threadIdx.x] = s;
    }
}

// exclusive scan over fine-bin totals -> bin_base[0..NB]
__global__ __launch_bounds__(1024) void kc_binscan(const unsigned int* __restrict__ bin_total,
                                                   unsigned int* __restrict__ bin_base) {
    __shared__ unsigned int s[1024];
    int i = threadIdx.x;
    unsigned int own = (i < NB) ? bin_total[i] : 0u;
    s[i] = own;
    __syncthreads();
    for (int off = 1; off < 1024; off <<= 1) {
        unsigned int add = (i >= off) ? s[i - off] : 0u;
        __syncthreads();
        s[i] += add;
        __syncthreads();
    }
    if (i < NB) bin_base[i] = s[i] - own;
    if (i == NB - 1) bin_base[NB] = s[i];
}

// LDS-staged CSR build: one block per 4096-chunk, 4 sequential bin phases.
// Scatter happens in LDS; global csr writes are contiguous coalesced streams.
__global__ __launch_bounds__(1024) void kc_csr2(
    const unsigned short* __restrict__ offs_T,
    const unsigned int* __restrict__ sorted,
    const unsigned char* __restrict__ cnt8,
    const unsigned int* __restrict__ bin_base,
    unsigned int* __restrict__ row_start,
    unsigned int* __restrict__ csr)
{
    __shared__ unsigned int stage[STAGE_CAP];   // 56 KB
    __shared__ unsigned int cursor[BIN_SIZE];   // 4 KB
    __shared__ unsigned int wsum2[16];
    const int t = threadIdx.x, lane = t & 63, wid = t >> 6;
    #pragma unroll 1
    for (int ph = 0; ph < 4; ++ph) {
        const int b = 4 * blockIdx.x + ph;
        if (b >= NB) break;
        const unsigned int base = bin_base[b];
        const unsigned int total = bin_base[b + 1] - base;
        // cnt prefix scan over the bin's 1024 vars (1 per thread)
        unsigned int cme = cnt8[(b << BIN_BITS) + t];
        unsigned int x = cme;
        #pragma unroll
        for (int off = 1; off < 64; off <<= 1) {
            unsigned int y = (unsigned int)__shfl_up((int)x, off);
            if (lane >= off) x += y;
        }
        if (lane == 63) wsum2[wid] = x;
        __syncthreads();
        unsigned int wbase = 0;
        for (int w = 0; w < wid; ++w) wbase += wsum2[w];
        unsigned int e = wbase + x - cme;         // exclusive prefix (bin-local)
        cursor[t] = e;
        row_start[(b << BIN_BITS) + t] = base + e;
        __syncthreads();
        // scatter the bin's spans into LDS stage
        for (int k = t; k < SBLK; k += 1024) {
            const int s0 = offs_T[(size_t)b * SBLK + k];
            const int s1 = offs_T[(size_t)(b + 1) * SBLK + k];
            const unsigned int* seg = sorted + (size_t)k * RSTRIDE;
            const unsigned int fbase = (unsigned int)k * (unsigned int)FPB;
            for (int e2 = s0; e2 < s1; ++e2) {
                unsigned int p = seg[e2];
                unsigned int slot = atomicAdd(&cursor[p & (BIN_SIZE - 1)], 1u);
                if (slot < (unsigned int)STAGE_CAP)
                    stage[slot] = ((fbase + (p >> 13)) << 1) | ((p >> 12) & 1u);
            }
        }
        __syncthreads();
        // contiguous coalesced write-out
        for (unsigned int i = t; i < total; i += 1024) csr[base + i] = stage[i];
        __syncthreads();
    }
}

// frontier walk: claim adjacent active functions; av-gated DIRECT decrement of packed;
// push touched. t==0 also zeroes eclaim (aliases dead offs_T; safe: first eclaim use
// is in kc_update t=0, a later launch).
__global__ void kc_funcs(const unsigned int* __restrict__ csr,
                         const unsigned int* __restrict__ row_start,
                         const unsigned char* __restrict__ cnt8,
                         unsigned int* __restrict__ fmask,
                         const int* __restrict__ vidx, const float* __restrict__ ef,
                         unsigned int* __restrict__ packed,
                         const unsigned char* __restrict__ av8,
                         unsigned int* __restrict__ touched,
                         unsigned int* __restrict__ counters,
                         const unsigned int* __restrict__ frontier,
                         unsigned int* __restrict__ eclaim, int t)
{
    const int gid = blockIdx.x * blockDim.x + threadIdx.x;
    const int gsz = gridDim.x * blockDim.x;
    if (t == 0) {
        for (int v = gid; v < Vn; v += gsz) eclaim[v] = 0u;
    }
    const unsigned int fcnt = counters[t];
    for (unsigned int i = gid; i < fcnt; i += gsz) {
        unsigned int v = frontier[i];
        unsigned int rs = row_start[v];
        unsigned int re = rs + cnt8[v];
        for (unsigned int j = rs; j < re; ++j) {
            unsigned int f = csr[j] >> 1;
            unsigned int w = f >> 5, m = 1u << (f & 31u);
            unsigned int old = atomicAnd(&fmask[w], ~m);
            if (old & m) {
                int e0 = 3 * (int)f;
                int a0 = vidx[e0], a1 = vidx[e0 + 1], a2 = vidx[e0 + 2];
                unsigned int s0 = ef[e0]     > 0.0f ? 1u : 0u;
                unsigned int s1 = ef[e0 + 1] > 0.0f ? 1u : 0u;
                unsigned int s2 = ef[e0 + 2] > 0.0f ? 1u : 0u;
                if (av8[a0]) atomicSub(&packed[a0], 0x10000u | s0);   // deg -= av-gated
                if (av8[a1]) atomicSub(&packed[a1], 0x10000u | s1);
                if (av8[a2]) atomicSub(&packed[a2], 0x10000u | s2);
                unsigned int b = atomicAdd(&counters[8 + t], 3u);
                if (b + 3u <= TCAP) {
                    touched[b] = (unsigned int)a0;
                    touched[b + 1] = (unsigned int)a1;
                    touched[b + 2] = (unsigned int)a2;
                }
            }
        }
    }
}

// sparse update: dedup (eclaim epoch); frontier vars deactivate; touched active vars
// tested for new-single -> next frontier. packed is read-only here.
__global__ void kc_update(const unsigned int* __restrict__ packed,
                          unsigned char* __restrict__ av8,
                          unsigned int* __restrict__ fep,
                          unsigned int* __restrict__ eclaim,
                          const unsigned int* __restrict__ touched,
                          const unsigned int* __restrict__ frontier_cur,
                          unsigned int* __restrict__ frontier_next,
                          unsigned int* __restrict__ counters, int t)
{
    const int gid = blockIdx.x * blockDim.x + threadIdx.x;
    const int gsz = gridDim.x * blockDim.x;
    const unsigned int fcnt = counters[t];
    unsigned int tc = counters[8 + t];
    const unsigned int tcnt = tc > TCAP ? TCAP : tc;
    const unsigned int total = fcnt + tcnt;
    const unsigned int epoch = (unsigned int)(t + 1);
    for (unsigned int i = gid; i < total; i += gsz) {
        unsigned int v = (i < fcnt) ? frontier_cur[i] : touched[i - fcnt];
        if (atomicExch(&eclaim[v], epoch) == epoch) continue;   // dedup within iteration
        if (fep[v] == epoch) { av8[v] = 0; continue; }          // was single -> deactivate
        if (av8[v]) {
            unsigned int p = packed[v];
            unsigned int cnt = p >> 16, pos = p & 0xFFFFu;
            if (pos == 0u || pos == cnt) {
                unsigned int ix = atomicAdd(&counters[t + 1], 1u);
                frontier_next[ix] = v;
                fep[v] = epoch + 1u;
            }
        }
    }
}

__global__ void kc_out(const unsigned int* __restrict__ packed, float* __restrict__ deg) {
    int v = blockIdx.x * blockDim.x + threadIdx.x;
    if (v < Vn) deg[v] = (float)(packed[v] >> 16);
}

// ======================= R8 fallback kernels (verbatim) =======================

__global__ __launch_bounds__(256) void k_pack_sort(
    const int* __restrict__ vidx, const float* __restrict__ ef,
    const float* __restrict__ afunc,
    unsigned long long* __restrict__ gpack,
    unsigned short* __restrict__ offs,
    unsigned short* __restrict__ sorted)
{
    __shared__ unsigned int hist[NBP];
    __shared__ unsigned int cur[NBP];
    __shared__ unsigned int wsum[4];

    const int k = blockIdx.x;
    const int f0 = k * FPB;
    int n = Fn - f0; if (n < 0) n = 0; if (n > FPB) n = FPB;
    const int n4 = n >> 2;

    for (int i = threadIdx.x; i < NBP; i += 256) hist[i] = 0u;
    __syncthreads();

    for (int j = threadIdx.x; j < n4; j += 256) {
        const int fb = f0 + 4 * j, e = 3 * fb;
        int4 va = *(const int4*)(vidx + e);
        int4 vb = *(const int4*)(vidx + e + 4);
        int4 vc = *(const int4*)(vidx + e + 8);
        float4 ea = *(const float4*)(ef + e);
        float4 eb = *(const float4*)(ef + e + 4);
        float4 ec = *(const float4*)(ef + e + 8);
        float4 a4 = *(const float4*)(afunc + fb);
        int   vv[12] = {va.x, va.y, va.z, va.w, vb.x, vb.y, vb.z, vb.w, vc.x, vc.y, vc.z, vc.w};
        float ss[12] = {ea.x, ea.y, ea.z, ea.w, eb.x, eb.y, eb.z, eb.w, ec.x, ec.y, ec.z, ec.w};
        float aa[4]  = {a4.x, a4.y, a4.z, a4.w};
        unsigned long long gq[4];
        #pragma unroll
        for (int q = 0; q < 4; ++q) {
            int v0 = vv[3 * q], v1 = vv[3 * q + 1], v2 = vv[3 * q + 2];
            unsigned int s0 = ss[3 * q]     > 0.0f ? 1u : 0u;
            unsigned int s1 = ss[3 * q + 1] > 0.0f ? 1u : 0u;
            unsigned int s2 = ss[3 * q + 2] > 0.0f ? 1u : 0u;
            unsigned int act = aa[q] != 0.0f ? 1u : 0u;
            gq[q] = (unsigned long long)(unsigned int)v0
                  | ((unsigned long long)(unsigned int)v1 << 20)
                  | ((unsigned long long)(unsigned int)v2 << 40)
                  | ((unsigned long long)s0 << 60)
                  | ((unsigned long long)s1 << 61)
                  | ((unsigned long long)s2 << 62)
                  | ((unsigned long long)act << 63);
            if (act) {
                atomicAdd(&hist[v0 >> BIN_BITS], 1u);
                atomicAdd(&hist[v1 >> BIN_BITS], 1u);
                atomicAdd(&hist[v2 >> BIN_BITS], 1u);
            }
        }
        *(ulonglong2*)(gpack + fb)     = make_ulonglong2(gq[0], gq[1]);
        *(ulonglong2*)(gpack + fb + 2) = make_ulonglong2(gq[2], gq[3]);
    }
    for (int i = 4 * n4 + threadIdx.x; i < n; i += 256) {
        const int f = f0 + i, e0 = 3 * f;
        int v0 = vidx[e0], v1 = vidx[e0 + 1], v2 = vidx[e0 + 2];
        unsigned int s0 = ef[e0]     > 0.0f ? 1u : 0u;
        unsigned int s1 = ef[e0 + 1] > 0.0f ? 1u : 0u;
        unsigned int s2 = ef[e0 + 2] > 0.0f ? 1u : 0u;
        unsigned int act = afunc[f] != 0.0f ? 1u : 0u;
        unsigned long long g = (unsigned long long)(unsigned int)v0
                             | ((unsigned long long)(unsigned int)v1 << 20)
                             | ((unsigned long long)(unsigned int)v2 << 40)
                             | ((unsigned long long)s0 << 60)
                             | ((unsigned long long)s1 << 61)
                             | ((unsigned long long)s2 << 62)
                             | ((unsigned long long)act << 63);
        gpack[f] = g;
        if (act) {
            atomicAdd(&hist[v0 >> BIN_BITS], 1u);
            atomicAdd(&hist[v1 >> BIN_BITS], 1u);
            atomicAdd(&hist[v2 >> BIN_BITS], 1u);
        }
    }
    __syncthreads();

    {
        const int t = threadIdx.x, lane = t & 63, wid = t >> 6;
        unsigned int a0 = hist[4 * t], a1 = hist[4 * t + 1];
        unsigned int a2 = hist[4 * t + 2], a3 = hist[4 * t + 3];
        unsigned int tsum = a0 + a1 + a2 + a3;
        unsigned int x = tsum;
        #pragma unroll
        for (int off = 1; off < 64; off <<= 1) {
            unsigned int y = (unsigned int)__shfl_up((int)x, off);
            if (lane >= off) x += y;
        }
        if (lane == 63) wsum[wid] = x;
        __syncthreads();
        unsigned int wbase = 0;
        for (int w = 0; w < wid; ++w) wbase += wsum[w];
        unsigned int e0x = wbase + x - tsum;
        unsigned int e1x = e0x + a0, e2x = e1x + a1, e3x = e2x + a2;
        cur[4 * t] = e0x; cur[4 * t + 1] = e1x; cur[4 * t + 2] = e2x; cur[4 * t + 3] = e3x;
        unsigned short* row = offs + (size_t)k * OROW;
        if (4 * t     <= NB) row[4 * t]     = (unsigned short)e0x;
        if (4 * t + 1 <= NB) row[4 * t + 1] = (unsigned short)e1x;
        if (4 * t + 2 <= NB) row[4 * t + 2] = (unsigned short)e2x;
        if (4 * t + 3 <= NB) row[4 * t + 3] = (unsigned short)e3x;
    }
    __syncthreads();

    const size_t rbase = (size_t)k * RSTRIDE;
    for (int j = threadIdx.x; j < n4; j += 256) {
        const int fb = f0 + 4 * j;
        ulonglong2 ga = *(const ulonglong2*)(gpack + fb);
        ulonglong2 gb = *(const ulonglong2*)(gpack + fb + 2);
        unsigned long long gq[4] = {ga.x, ga.y, gb.x, gb.y};
        #pragma unroll
        for (int q = 0; q < 4; ++q) {
            unsigned long long g = gq[q];
            if ((long long)g < 0) {
                unsigned int v0 = (unsigned int)(g & 0xFFFFFu);
                unsigned int v1 = (unsigned int)((g >> 20) & 0xFFFFFu);
                unsigned int v2 = (unsigned int)((g >> 40) & 0xFFFFFu);
                unsigned int sl0 = atomicAdd(&cur[v0 >> BIN_BITS], 1u);
                sorted[rbase + sl0] = (unsigned short)((v0 & (CH_SIZE - 1)) | ((unsigned int)((g >> 60) & 1u) << CH_BITS));
                unsigned int sl1 = atomicAdd(&cur[v1 >> BIN_BITS], 1u);
                sorted[rbase + sl1] = (unsigned short)((v1 & (CH_SIZE - 1)) | ((unsigned int)((g >> 61) & 1u) << CH_BITS));
                unsigned int sl2 = atomicAdd(&cur[v2 >> BIN_BITS], 1u);
                sorted[rbase + sl2] = (unsigned short)((v2 & (CH_SIZE - 1)) | ((unsigned int)((g >> 62) & 1u) << CH_BITS));
            }
        }
    }
    for (int i = 4 * n4 + threadIdx.x; i < n; i += 256) {
        unsigned long long g = gpack[f0 + i];
        if ((long long)g < 0) {
            unsigned int v0 = (unsigned int)(g & 0xFFFFFu);
            unsigned int v1 = (unsigned int)((g >> 20) & 0xFFFFFu);
            unsigned int v2 = (unsigned int)((g >> 40) & 0xFFFFFu);
            unsigned int sl0 = atomicAdd(&cur[v0 >> BIN_BITS], 1u);
            sorted[rbase + sl0] = (unsigned short)((v0 & (CH_SIZE - 1)) | ((unsigned int)((g >> 60) & 1u) << CH_BITS));
            unsigned int sl1 = atomicAdd(&cur[v1 >> BIN_BITS], 1u);
            sorted[rbase + sl1] = (unsigned short)((v1 & (CH_SIZE - 1)) | ((unsigned int)((g >> 61) & 1u) << CH_BITS));
            unsigned int sl2 = atomicAdd(&cur[v2 >> BIN_BITS], 1u);
            sorted[rbase + sl2] = (unsigned short)((v2 & (CH_SIZE - 1)) | ((unsigned int)((g >> 62) & 1u) << CH_BITS));
        }
    }
}

__global__ __launch_bounds__(1024) void k_accum(
    const unsigned short* __restrict__ offs_T,
    const unsigned short* __restrict__ sorted,
    const float* __restrict__ avars,
    unsigned int* __restrict__ packed,
    unsigned long long* __restrict__ avm,
    unsigned long long* __restrict__ svm,
    unsigned char* __restrict__ sgrp)
{
    __shared__ unsigned int acc[CH_SIZE];
    __shared__ unsigned short row0[SBLK];
    __shared__ unsigned short row1[SBLK];
    const int c = blockIdx.x;
    const int r0 = 4 * c;
    const int r1 = (4 * c + 4 < NB) ? (4 * c + 4) : NB;
    for (int i = threadIdx.x; i < CH_SIZE; i += 1024) acc[i] = 0u;
    for (int i = threadIdx.x; i < SBLK; i += 1024) {
        row0[i] = offs_T[(size_t)r0 * SBLK + i];
        row1[i] = offs_T[(size_t)r1 * SBLK + i];
    }
    __syncthreads();
    for (int k = threadIdx.x; k < SBLK; k += 1024) {
        const int s0 = row0[k], s1 = row1[k];
        const unsigned short* seg = sorted + (size_t)k * RSTRIDE;
        for (int e = s0; e < s1; ++e) {
            unsigned int p = seg[e];
            atomicAdd(&acc[p & (CH_SIZE - 1)], 0x10000u | (p >> CH_BITS));
        }
    }
    __syncthreads();
    const int vbase = c << CH_BITS;
    for (int i = threadIdx.x; i < CH_SIZE; i += 1024) {
        int v = vbase + i;
        bool valid = v < Vn;
        unsigned int p = valid ? acc[i] : 0u;
        bool av = valid && (avars[v] != 0.0f);
        unsigned int cnt = p >> 16, pos = p & 0xFFFFu;
        bool sv = av && (pos == 0u || pos == cnt);
        unsigned long long avb = __ballot(av);
        unsigned long long svb = __ballot(sv);
        if (valid) packed[v] = p;
        if ((threadIdx.x & 63) == 0) {
            avm[v >> 6] = avb;
            svm[v >> 6] = svb;
            sgrp[v >> 6] = (svb != 0ull) ? 1 : 0;
        }
    }
}

__global__ void k_zero_tmp(unsigned int* __restrict__ tmp, unsigned char* __restrict__ tgrp) {
    int v = blockIdx.x * blockDim.x + threadIdx.x;
    if (v < Vn) tmp[v] = 0u;
    if (v < AVW) tgrp[v] = 0;
}

__device__ __forceinline__ void fire_one(unsigned long long g, int f,
                                         unsigned long long* __restrict__ gpack,
                                         const unsigned int* __restrict__ svm32,
                                         const unsigned char* __restrict__ sgrp,
                                         unsigned int* __restrict__ tmp,
                                         unsigned char* __restrict__ tgrp)
{
    if ((long long)g >= 0) return;
    unsigned int v0 = (unsigned int)(g & 0xFFFFFu);
    unsigned int v1 = (unsigned int)((g >> 20) & 0xFFFFFu);
    unsigned int v2 = (unsigned int)((g >> 40) & 0xFFFFFu);
    if (!(sgrp[v0 >> 6] | sgrp[v1 >> 6] | sgrp[v2 >> 6])) return;
    unsigned int hit = ((svm32[v0 >> 5] >> (v0 & 31u)) |
                        (svm32[v1 >> 5] >> (v1 & 31u)) |
                        (svm32[v2 >> 5] >> (v2 & 31u))) & 1u;
    if (!hit) return;
    gpack[f] = g & ~(1ull << 63);
    atomicAdd(&tmp[v0], 0x10000u | (unsigned int)((g >> 60) & 1u));
    atomicAdd(&tmp[v1], 0x10000u | (unsigned int)((g >> 61) & 1u));
    atomicAdd(&tmp[v2], 0x10000u | (unsigned int)((g >> 62) & 1u));
    tgrp[v0 >> 6] = 1; tgrp[v1 >> 6] = 1; tgrp[v2 >> 6] = 1;
}

__global__ void k_funcs(unsigned long long* __restrict__ gpack,
                        const unsigned int* __restrict__ svm32,
                        const unsigned char* __restrict__ sgrp,
                        unsigned int* __restrict__ tmp,
                        unsigned char* __restrict__ tgrp)
{
    int gid = blockIdx.x * blockDim.x + threadIdx.x;
    int f = 2 * gid;
    if (f >= Fn) return;
    ulonglong2 g2 = *(const ulonglong2*)(gpack + f);
    fire_one(g2.x, f,     gpack, svm32, sgrp, tmp, tgrp);
    fire_one(g2.y, f + 1, gpack, svm32, sgrp, tmp, tgrp);
}

__global__ void k_update(unsigned int* __restrict__ packed,
                         unsigned int* __restrict__ tmp,
                         unsigned long long* __restrict__ avm,
                         unsigned long long* __restrict__ svm,
                         unsigned char* __restrict__ sgrp,
                         unsigned char* __restrict__ tgrp,
                         float* __restrict__ deg, int write_deg)
{
    int v = blockIdx.x * blockDim.x + threadIdx.x;
    int lane = threadIdx.x & 63;
    bool valid = v < Vn;
    unsigned long long avw = 0ull, svw = 0ull;
    unsigned char tg = 0;
    if (valid) {
        avw = avm[v >> 6]; svw = svm[v >> 6];
        tg = tgrp[v >> 6];
    }
    bool av_old = valid && ((avw >> lane) & 1ull);
    bool sv     = valid && ((svw >> lane) & 1ull);
    bool av_new = av_old && !sv;
    unsigned int p = 0u;
    if (valid) {
        p = packed[v];
        if (tg) {
            unsigned int tp = tmp[v];
            if (tp != 0u) {
                if (av_old) { p -= tp; packed[v] = p; }
                tmp[v] = 0u;
            }
        }
    }
    unsigned int c = p >> 16, pos = p & 0xFFFFu;
    bool nsv = av_new && (pos == 0u || pos == c);
    unsigned long long nsvb = __ballot(nsv);
    if (lane == 0 && valid) {
        svm[v >> 6] = nsvb;
        avm[v >> 6] = avw & ~svw;
        sgrp[v >> 6] = (nsvb != 0ull) ? 1 : 0;
        if (tg) tgrp[v >> 6] = 0;
    }
    if (write_deg && valid) deg[v] = (float)c;
}

// ======================= launcher =======================
extern "C" void kernel_launch(void* const* d_in, const int* in_sizes, int n_in,
                              void* d_out, int out_size, void* d_ws, size_t ws_size,
                              hipStream_t stream) {
    const int*   graph_map        = (const int*)d_in[0];
    const float* edge_feature     = (const float*)d_in[1];
    const float* active_variables = (const float*)d_in[2];
    const float* active_functions = (const float*)d_in[3];
    const int* vidx = graph_map;
    float* deg = (float*)d_out;
    char* ws = (char*)d_ws;

    const int BS = 256;
    const int gV = (Vn + BS - 1) / BS;
    const int gF = (Fn + BS - 1) / BS;

    // ---- CSR-path workspace requirement (identical to R10's NEED, which ran) ----
    const size_t szA   = 4ull * SBLK * RSTRIDE;       // u32 regions (alias: frontB/touched after kc_csr2)
    const size_t szB   = 2ull * 2ull * SBLK * OROW;   // offs + offs_T (offs_T aliases eclaim after kc_csr2)
    const size_t szC   = 4ull * NCH * CH_SIZE;        // packed (padded)
    const size_t szD   = 4ull * En;                   // csr
    const size_t szE   = 4ull * NCH * CH_SIZE;        // row_start
    const size_t szF   = 1ull * NCH * CH_SIZE;        // cnt8
    const size_t szFep = 4ull * Vn;
    const size_t szAv8 = 1ull * NCH * CH_SIZE;
    const size_t szFrA = 4ull * Vn;
    const size_t szFm  = 4ull * ((FWORDS + 127) & ~127);
    const size_t szMisc = 65536;
    const size_t NEED = szA + szB + szC + szD + szE + szF + szFep + szAv8 + szFrA + szFm + szMisc;

    if (ws_size >= NEED) {
        // ================= CSR / frontier path =================
        size_t off = 0;
        unsigned int* regions32 = (unsigned int*)(ws + off); off += szA;
        unsigned int* frontB  = (unsigned int*)((char*)regions32);                // 4 MB (dead sorted)
        unsigned int* touched = (unsigned int*)((char*)regions32 + 4ull * Vn);    // 32 MB (dead sorted)
        unsigned short* offs   = (unsigned short*)(ws + off); off += 2ull * SBLK * OROW;
        unsigned short* offs_T = (unsigned short*)(ws + off); off += 2ull * SBLK * OROW;
        unsigned int* eclaim = (unsigned int*)offs_T;         // 4 MB alias (dead after kc_csr2; zeroed in funcs_0)
        unsigned int* packed   = (unsigned int*)(ws + off); off += szC;
        unsigned int* csr      = (unsigned int*)(ws + off); off += szD;
        unsigned int* row_start = (unsigned int*)(ws + off); off += szE;
        unsigned char* cnt8     = (unsigned char*)(ws + off); off += szF;
        unsigned int* fep       = (unsigned int*)(ws + off); off += szFep;
        unsigned char* av8      = (unsigned char*)(ws + off); off += szAv8;
        unsigned int* frontA    = (unsigned int*)(ws + off); off += szFrA;
        unsigned int* fmask     = (unsigned int*)(ws + off); off += szFm;
        unsigned int* counters  = (unsigned int*)(ws + off); off += 4096;
        unsigned int* bin_total = (unsigned int*)(ws + off); off += 4096;
        unsigned int* bin_base  = (unsigned int*)(ws + off); off += 4096;

        kc_init<<<gF, BS, 0, stream>>>(active_functions, fmask, fep, counters);
        kc_pack_sort<<<SBLK, 256, 0, stream>>>(vidx, edge_feature, active_functions, offs, regions32);
        k_transpose<<<dim3(OROW / 64, SBLK / 64), 256, 0, stream>>>(offs, offs_T);
        kc_accum<<<NCH, 1024, 0, stream>>>(offs_T, regions32, active_variables, packed,
                                           av8, cnt8, frontA, counters, fep, bin_total);
        kc_binscan<<<1, 1024, 0, stream>>>(bin_total, bin_base);
        kc_csr2<<<NCH, 1024, 0, stream>>>(offs_T, regions32, cnt8, bin_base, row_start, csr);
        for (int t = 0; t < Tn; ++t) {
            const unsigned int* fcur = (t & 1) ? frontB : frontA;
            unsigned int* fnext = (t & 1) ? frontA : frontB;
            kc_funcs<<<256, 256, 0, stream>>>(csr, row_start, cnt8, fmask, vidx, edge_feature,
                                              packed, av8, touched, counters, fcur, eclaim, t);
            if (t < Tn - 1)
                kc_update<<<256, 256, 0, stream>>>(packed, av8, fep, eclaim, touched,
                                                   fcur, fnext, counters, t);
        }
        kc_out<<<gV, BS, 0, stream>>>(packed, deg);
    } else {
        // ================= R8 fallback path =================
        size_t off = 0;
        unsigned long long* gpack = (unsigned long long*)(ws + off); off += 8ull * Fn;
        unsigned int* packed      = (unsigned int*)(ws + off);       off += 4ull * Vn;
        unsigned long long* avm   = (unsigned long long*)(ws + off); off += 8ull * AVW;
        unsigned long long* svm   = (unsigned long long*)(ws + off); off += 8ull * AVW;
        unsigned char* sgrp       = (unsigned char*)(ws + off);      off += (size_t)((AVW + 255) & ~255);
        unsigned char* tgrp       = (unsigned char*)(ws + off);      off += (size_t)((AVW + 255) & ~255);
        unsigned short* offs      = (unsigned short*)(ws + off);     off += 2ull * SBLK * OROW;
        unsigned short* offs_T    = (unsigned short*)(ws + off);     off += 2ull * SBLK * OROW;
        unsigned short* sorted    = (unsigned short*)(ws + off);     off += 2ull * SBLK * RSTRIDE;
        unsigned int* tmp = (unsigned int*)sorted;

        const int gF2 = (Fn / 2 + BS - 1) / BS;
        k_pack_sort<<<SBLK, 256, 0, stream>>>(vidx, edge_feature, active_functions, gpack, offs, sorted);
        k_transpose<<<dim3(OROW / 64, SBLK / 64), 256, 0, stream>>>(offs, offs_T);
        k_accum<<<NCH, 1024, 0, stream>>>(offs_T, sorted, active_variables, packed, avm, svm, sgrp);
        k_zero_tmp<<<gV, BS, 0, stream>>>(tmp, tgrp);
        for (int t = 0; t < Tn; ++t) {
            k_funcs<<<gF2, BS, 0, stream>>>(gpack, (const unsigned int*)svm, sgrp, tmp, tgrp);
            k_update<<<gV, BS, 0, stream>>>(packed, tmp, avm, svm, sgrp, tgrp, deg, (t == Tn - 1) ? 1 : 0);
        }
    }
}

// Round 12
// 547.270 us; speedup vs baseline: 1.4706x; 1.1281x over previous
//
#include <hip/hip_runtime.h>

// Peeling propagation on bipartite graph. V=1e6, F=4.2e6, K=3 (edge e -> function e/3).
// T=5. Output: deg (V floats) in d_out.
//
// R12 (CSR/frontier path, ws-gated; fallback = R8 verbatim):
//  * kc_pack_sort: R11's gsave[jj] dynamic local-array indexing spilled to SCRATCH
//    (hidden ~200us of global traffic). Now three FIXED register quads with static
//    guards -> true register carry.
//  * kc_build: merged accum + binscan + csr2. One span walk per bin (pass B is
//    L2-warm), LDS-staged scatter, FIXED per-bin csr capacity (13888 = +8.7 sigma)
//    removes the global-scan dependency. XCD-swizzled chunk mapping keeps
//    boundary-line sharing within one XCD.
//  * row_start aliases dead offs; NEED <= R11's proven 128.27 MB.

static constexpr int Vn = 1000000;
static constexpr int Fn = 4200000;
static constexpr int En = 3 * Fn;                          // 12.6M edges
static constexpr int Tn = 5;

static constexpr int SBLK = 2048;                          // sort blocks / regions
static constexpr int FPB  = 2052;                          // functions/block (mult of 4)
static constexpr int BIN_BITS = 10;                        // fine bin = 1024 vars
static constexpr int BIN_SIZE = 1 << BIN_BITS;
static constexpr int NB  = (Vn + BIN_SIZE - 1) >> BIN_BITS;   // 977 fine bins
static constexpr int NBP = 1024;
static constexpr int CH_BITS = 12;                         // chunk = 4096 vars (R8 fallback + build phases)
static constexpr int CH_SIZE = 1 << CH_BITS;
static constexpr int NCH = (Vn + CH_SIZE - 1) >> CH_BITS;  // 245 chunks
static constexpr int RCAP = 3 * FPB;
static constexpr int RSTRIDE = (RCAP + 63) & ~63;          // 6208
static constexpr int OROW = 1024;
static constexpr int AVW = NCH * (CH_SIZE / 64);           // R8 mask words
static constexpr unsigned int TCAP = 8u * 1024u * 1024u;   // touched-list capacity
static constexpr int FWORDS = Fn / 32;                     // 131250 fmask words
static constexpr unsigned int CAP_BIN = 13888;             // fixed csr entries/bin (exp 12897, +8.7sigma)

// ======================= shared: transpose =======================
__global__ __launch_bounds__(256) void k_transpose(const unsigned short* __restrict__ in,
                                                   unsigned short* __restrict__ out) {
    __shared__ unsigned short t[64][65];
    const int bx = blockIdx.x, by = blockIdx.y;
    for (int i = threadIdx.x; i < 64 * 64; i += 256) {
        int r = i >> 6, c = i & 63;
        t[r][c] = in[(size_t)(by * 64 + r) * OROW + (bx * 64 + c)];
    }
    __syncthreads();
    for (int i = threadIdx.x; i < 64 * 64; i += 256) {
        int r = i >> 6, c = i & 63;
        out[(size_t)(bx * 64 + r) * SBLK + (by * 64 + c)] = t[c][r];
    }
}

// ======================= CSR-path kernels =======================

// fused init: fmask ballots + zero fep + zero counters
__global__ void kc_init(const float* __restrict__ afunc, unsigned int* __restrict__ fmask,
                        unsigned int* __restrict__ fep, unsigned int* __restrict__ counters) {
    int f = blockIdx.x * blockDim.x + threadIdx.x;
    bool act = (f < Fn) && (afunc[f] != 0.0f);
    unsigned long long b = __ballot(act);
    int lane = threadIdx.x & 63;
    if (f < Fn) {
        int w = f >> 5;
        if (lane == 0)  fmask[w] = (unsigned int)b;
        if (lane == 32) fmask[w] = (unsigned int)(b >> 32);
    }
    if (f < Vn) fep[f] = 0u;
    if (f < 64) counters[f] = 0u;
}

// helpers: fixed register quad (fully unrolled -> no scratch)
__device__ __forceinline__ void load_quad(
    const int* __restrict__ vidx, const float* __restrict__ ef,
    const float* __restrict__ afunc, int fb,
    unsigned long long (&g)[4], unsigned int* hist)
{
    const int e = 3 * fb;
    int4 va = *(const int4*)(vidx + e);
    int4 vb = *(const int4*)(vidx + e + 4);
    int4 vc = *(const int4*)(vidx + e + 8);
    float4 ea = *(const float4*)(ef + e);
    float4 eb = *(const float4*)(ef + e + 4);
    float4 ec = *(const float4*)(ef + e + 8);
    float4 a4 = *(const float4*)(afunc + fb);
    int   vv[12] = {va.x, va.y, va.z, va.w, vb.x, vb.y, vb.z, vb.w, vc.x, vc.y, vc.z, vc.w};
    float ss[12] = {ea.x, ea.y, ea.z, ea.w, eb.x, eb.y, eb.z, eb.w, ec.x, ec.y, ec.z, ec.w};
    float aa[4]  = {a4.x, a4.y, a4.z, a4.w};
    #pragma unroll
    for (int q = 0; q < 4; ++q) {
        int v0 = vv[3 * q], v1 = vv[3 * q + 1], v2 = vv[3 * q + 2];
        unsigned int s0 = ss[3 * q]     > 0.0f ? 1u : 0u;
        unsigned int s1 = ss[3 * q + 1] > 0.0f ? 1u : 0u;
        unsigned int s2 = ss[3 * q + 2] > 0.0f ? 1u : 0u;
        unsigned int act = aa[q] != 0.0f ? 1u : 0u;
        g[q] = (unsigned long long)(unsigned int)v0
             | ((unsigned long long)(unsigned int)v1 << 20)
             | ((unsigned long long)(unsigned int)v2 << 40)
             | ((unsigned long long)s0 << 60)
             | ((unsigned long long)s1 << 61)
             | ((unsigned long long)s2 << 62)
             | ((unsigned long long)act << 63);
        if (act) {
            atomicAdd(&hist[v0 >> BIN_BITS], 1u);
            atomicAdd(&hist[v1 >> BIN_BITS], 1u);
            atomicAdd(&hist[v2 >> BIN_BITS], 1u);
        }
    }
}

__device__ __forceinline__ void scatter_quad(
    const unsigned long long (&g)[4], int j4 /* = 4*j */,
    unsigned int* cur, unsigned int* __restrict__ sorted, size_t rbase)
{
    #pragma unroll
    for (int q = 0; q < 4; ++q) {
        unsigned long long gg = g[q];
        if ((long long)gg < 0) {
            unsigned int fr = (unsigned int)(j4 + q) << 13;
            unsigned int v0 = (unsigned int)(gg & 0xFFFFFu);
            unsigned int v1 = (unsigned int)((gg >> 20) & 0xFFFFFu);
            unsigned int v2 = (unsigned int)((gg >> 40) & 0xFFFFFu);
            unsigned int sl0 = atomicAdd(&cur[v0 >> BIN_BITS], 1u);
            sorted[rbase + sl0] = (v0 & (CH_SIZE - 1)) | ((unsigned int)((gg >> 60) & 1u) << 12) | fr;
            unsigned int sl1 = atomicAdd(&cur[v1 >> BIN_BITS], 1u);
            sorted[rbase + sl1] = (v1 & (CH_SIZE - 1)) | ((unsigned int)((gg >> 61) & 1u) << 12) | fr;
            unsigned int sl2 = atomicAdd(&cur[v2 >> BIN_BITS], 1u);
            sorted[rbase + sl2] = (v2 & (CH_SIZE - 1)) | ((unsigned int)((gg >> 62) & 1u) << 12) | fr;
        }
    }
}

// pack+hist+scan+scatter with FIXED register quads (no scratch, no gpack staging).
// sorted entry (u32): v_local12 | sign<<12 | fid_rel<<13
__global__ __launch_bounds__(256) void kc_pack_sort(
    const int* __restrict__ vidx, const float* __restrict__ ef,
    const float* __restrict__ afunc,
    unsigned short* __restrict__ offs,
    unsigned int* __restrict__ sorted)
{
    __shared__ unsigned int hist[NBP];
    __shared__ unsigned int cur[NBP];
    __shared__ unsigned int wsum[4];

    const int k = blockIdx.x;
    const int f0 = k * FPB;
    int n = Fn - f0; if (n < 0) n = 0; if (n > FPB) n = FPB;   // always %4==0
    const int n4 = n >> 2;                                     // <= 513

    for (int i = threadIdx.x; i < NBP; i += 256) hist[i] = 0u;
    __syncthreads();

    unsigned long long q0[4], q1[4], q2[4];
    const int j0 = threadIdx.x, j1 = threadIdx.x + 256, j2 = threadIdx.x + 512;
    const bool h0 = j0 < n4, h1 = j1 < n4, h2 = j2 < n4;

    if (h0) load_quad(vidx, ef, afunc, f0 + 4 * j0, q0, hist);
    if (h1) load_quad(vidx, ef, afunc, f0 + 4 * j1, q1, hist);
    if (h2) load_quad(vidx, ef, afunc, f0 + 4 * j2, q2, hist);
    __syncthreads();

    // shuffle-based exclusive scan over 1024 fine bins
    {
        const int t = threadIdx.x, lane = t & 63, wid = t >> 6;
        unsigned int a0 = hist[4 * t], a1 = hist[4 * t + 1];
        unsigned int a2 = hist[4 * t + 2], a3 = hist[4 * t + 3];
        unsigned int tsum = a0 + a1 + a2 + a3;
        unsigned int x = tsum;
        #pragma unroll
        for (int off = 1; off < 64; off <<= 1) {
            unsigned int y = (unsigned int)__shfl_up((int)x, off);
            if (lane >= off) x += y;
        }
        if (lane == 63) wsum[wid] = x;
        __syncthreads();
        unsigned int wbase = 0;
        for (int w = 0; w < wid; ++w) wbase += wsum[w];
        unsigned int e0x = wbase + x - tsum;
        unsigned int e1x = e0x + a0, e2x = e1x + a1, e3x = e2x + a2;
        cur[4 * t] = e0x; cur[4 * t + 1] = e1x; cur[4 * t + 2] = e2x; cur[4 * t + 3] = e3x;
        unsigned short* row = offs + (size_t)k * OROW;
        if (4 * t     <= NB) row[4 * t]     = (unsigned short)e0x;
        if (4 * t + 1 <= NB) row[4 * t + 1] = (unsigned short)e1x;
        if (4 * t + 2 <= NB) row[4 * t + 2] = (unsigned short)e2x;
        if (4 * t + 3 <= NB) row[4 * t + 3] = (unsigned short)e3x;
    }
    __syncthreads();

    const size_t rbase = (size_t)k * RSTRIDE;
    if (h0) scatter_quad(q0, 4 * j0, cur, sorted, rbase);
    if (h1) scatter_quad(q1, 4 * j1, cur, sorted, rbase);
    if (h2) scatter_quad(q2, 4 * j2, cur, sorted, rbase);
}

// merged accumulate + per-bin CSR build. Per chunk (XCD-swizzled), 4 bin phases:
// pass A (LDS accumulate) -> scan (cursor, packed/av8/cnt8/row_start/frontier) ->
// pass B (L2-warm span re-walk, LDS-staged scatter) -> coalesced csr segment write.
__global__ __launch_bounds__(1024) void kc_build(
    const unsigned short* __restrict__ offs_T,
    const unsigned int* __restrict__ sorted,
    const float* __restrict__ avars,
    unsigned int* __restrict__ packed,
    unsigned char* __restrict__ av8,
    unsigned char* __restrict__ cnt8,
    unsigned int* __restrict__ row_start,
    unsigned int* __restrict__ csr,
    unsigned int* __restrict__ frontA,
    unsigned int* __restrict__ counters,
    unsigned int* __restrict__ fep)
{
    __shared__ unsigned int stage[CAP_BIN];      // 55,552 B
    __shared__ unsigned int acc[BIN_SIZE];       // 4 KB (doubles as cursor in pass B)
    __shared__ unsigned short rows[5][SBLK];     // 20,480 B
    __shared__ unsigned int wsum2[16];
    __shared__ unsigned int sh_total;

    // XCD swizzle: 31 consecutive chunks per XCD (grid = 248, round-robin bid->XCD)
    const int bid = blockIdx.x;
    const int c = (bid & 7) * 31 + (bid >> 3);
    if (c >= NCH) return;

    for (int r = 0; r < 5; ++r) {
        int rr = 4 * c + r; if (rr > NB) rr = NB;
        for (int i = threadIdx.x; i < SBLK; i += 1024)
            rows[r][i] = offs_T[(size_t)rr * SBLK + i];
    }
    const int t = threadIdx.x, lane = t & 63, wid = t >> 6;

    #pragma unroll 1
    for (int ph = 0; ph < 4; ++ph) {
        const int b = 4 * c + ph;
        if (b >= NB) break;
        acc[t] = 0u;
        __syncthreads();
        // pass A: accumulate (count<<16 | positives) per bin-local var
        for (int k = t; k < SBLK; k += 1024) {
            const int s0 = rows[ph][k], s1 = rows[ph + 1][k];
            const unsigned int* seg = sorted + (size_t)k * RSTRIDE;
            for (int e = s0; e < s1; ++e) {
                unsigned int p = seg[e];
                atomicAdd(&acc[p & (BIN_SIZE - 1)], 0x10000u | ((p >> 12) & 1u));
            }
        }
        __syncthreads();
        // scan counts -> exclusive prefix; per-var outputs
        unsigned int pk = acc[t];
        unsigned int cnt = pk >> 16, pos = pk & 0xFFFFu;
        unsigned int x = cnt;
        #pragma unroll
        for (int off = 1; off < 64; off <<= 1) {
            unsigned int y = (unsigned int)__shfl_up((int)x, off);
            if (lane >= off) x += y;
        }
        if (lane == 63) wsum2[wid] = x;
        __syncthreads();
        unsigned int wbase = 0;
        for (int w = 0; w < wid; ++w) wbase += wsum2[w];
        const unsigned int e0 = wbase + x - cnt;     // bin-local exclusive prefix
        const int v = (b << BIN_BITS) + t;
        if (v < Vn) {
            packed[v] = pk;
            bool av = avars[v] != 0.0f;
            av8[v] = av ? 1 : 0;
            cnt8[v] = (unsigned char)(cnt > 255u ? 255u : cnt);
            row_start[v] = (unsigned int)b * CAP_BIN + e0;
            if (av && (pos == 0u || pos == cnt)) {          // initial single_v
                unsigned int ix = atomicAdd(&counters[0], 1u);
                frontA[ix] = (unsigned int)v;
                fep[v] = 1u;
            }
        }
        if (t == 1023) sh_total = e0 + cnt;
        __syncthreads();
        acc[t] = e0;                                        // cursor for pass B
        __syncthreads();
        // pass B: scatter fid entries into LDS stage (spans L2-warm from pass A)
        for (int k = t; k < SBLK; k += 1024) {
            const int s0 = rows[ph][k], s1 = rows[ph + 1][k];
            const unsigned int* seg = sorted + (size_t)k * RSTRIDE;
            const unsigned int fbase = (unsigned int)k * (unsigned int)FPB;
            for (int e = s0; e < s1; ++e) {
                unsigned int p = seg[e];
                unsigned int slot = atomicAdd(&acc[p & (BIN_SIZE - 1)], 1u);
                if (slot < CAP_BIN)
                    stage[slot] = ((fbase + (p >> 13)) << 1) | ((p >> 12) & 1u);
            }
        }
        __syncthreads();
        unsigned int total = sh_total;
        if (total > CAP_BIN) total = CAP_BIN;
        for (unsigned int i = t; i < total; i += 1024)
            csr[(size_t)b * CAP_BIN + i] = stage[i];
        __syncthreads();
    }
}

// frontier walk: claim adjacent active functions; av-gated DIRECT decrement of packed;
// push touched. t==0 also zeroes eclaim (aliases dead offs_T).
__global__ void kc_funcs(const unsigned int* __restrict__ csr,
                         const unsigned int* __restrict__ row_start,
                         const unsigned char* __restrict__ cnt8,
                         unsigned int* __restrict__ fmask,
                         const int* __restrict__ vidx, const float* __restrict__ ef,
                         unsigned int* __restrict__ packed,
                         const unsigned char* __restrict__ av8,
                         unsigned int* __restrict__ touched,
                         unsigned int* __restrict__ counters,
                         const unsigned int* __restrict__ frontier,
                         unsigned int* __restrict__ eclaim, int t)
{
    const int gid = blockIdx.x * blockDim.x + threadIdx.x;
    const int gsz = gridDim.x * blockDim.x;
    if (t == 0) {
        for (int v = gid; v < Vn; v += gsz) eclaim[v] = 0u;
    }
    const unsigned int fcnt = counters[t];
    for (unsigned int i = gid; i < fcnt; i += gsz) {
        unsigned int v = frontier[i];
        unsigned int rs = row_start[v];
        unsigned int re = rs + cnt8[v];
        for (unsigned int j = rs; j < re; ++j) {
            unsigned int f = csr[j] >> 1;
            unsigned int w = f >> 5, m = 1u << (f & 31u);
            unsigned int old = atomicAnd(&fmask[w], ~m);
            if (old & m) {
                int e0 = 3 * (int)f;
                int a0 = vidx[e0], a1 = vidx[e0 + 1], a2 = vidx[e0 + 2];
                unsigned int s0 = ef[e0]     > 0.0f ? 1u : 0u;
                unsigned int s1 = ef[e0 + 1] > 0.0f ? 1u : 0u;
                unsigned int s2 = ef[e0 + 2] > 0.0f ? 1u : 0u;
                if (av8[a0]) atomicSub(&packed[a0], 0x10000u | s0);   // deg -= av-gated
                if (av8[a1]) atomicSub(&packed[a1], 0x10000u | s1);
                if (av8[a2]) atomicSub(&packed[a2], 0x10000u | s2);
                unsigned int bofs = atomicAdd(&counters[8 + t], 3u);
                if (bofs + 3u <= TCAP) {
                    touched[bofs] = (unsigned int)a0;
                    touched[bofs + 1] = (unsigned int)a1;
                    touched[bofs + 2] = (unsigned int)a2;
                }
            }
        }
    }
}

// sparse update: dedup (eclaim epoch); frontier vars deactivate; touched active vars
// tested for new-single -> next frontier. packed read-only here.
__global__ void kc_update(const unsigned int* __restrict__ packed,
                          unsigned char* __restrict__ av8,
                          unsigned int* __restrict__ fep,
                          unsigned int* __restrict__ eclaim,
                          const unsigned int* __restrict__ touched,
                          const unsigned int* __restrict__ frontier_cur,
                          unsigned int* __restrict__ frontier_next,
                          unsigned int* __restrict__ counters, int t)
{
    const int gid = blockIdx.x * blockDim.x + threadIdx.x;
    const int gsz = gridDim.x * blockDim.x;
    const unsigned int fcnt = counters[t];
    unsigned int tc = counters[8 + t];
    const unsigned int tcnt = tc > TCAP ? TCAP : tc;
    const unsigned int total = fcnt + tcnt;
    const unsigned int epoch = (unsigned int)(t + 1);
    for (unsigned int i = gid; i < total; i += gsz) {
        unsigned int v = (i < fcnt) ? frontier_cur[i] : touched[i - fcnt];
        if (atomicExch(&eclaim[v], epoch) == epoch) continue;   // dedup within iteration
        if (fep[v] == epoch) { av8[v] = 0; continue; }          // was single -> deactivate
        if (av8[v]) {
            unsigned int p = packed[v];
            unsigned int cnt = p >> 16, pos = p & 0xFFFFu;
            if (pos == 0u || pos == cnt) {
                unsigned int ix = atomicAdd(&counters[t + 1], 1u);
                frontier_next[ix] = v;
                fep[v] = epoch + 1u;
            }
        }
    }
}

__global__ void kc_out(const unsigned int* __restrict__ packed, float* __restrict__ deg) {
    int v = blockIdx.x * blockDim.x + threadIdx.x;
    if (v < Vn) deg[v] = (float)(packed[v] >> 16);
}

// ======================= R8 fallback kernels (verbatim) =======================

__global__ __launch_bounds__(256) void k_pack_sort(
    const int* __restrict__ vidx, const float* __restrict__ ef,
    const float* __restrict__ afunc,
    unsigned long long* __restrict__ gpack,
    unsigned short* __restrict__ offs,
    unsigned short* __restrict__ sorted)
{
    __shared__ unsigned int hist[NBP];
    __shared__ unsigned int cur[NBP];
    __shared__ unsigned int wsum[4];

    const int k = blockIdx.x;
    const int f0 = k * FPB;
    int n = Fn - f0; if (n < 0) n = 0; if (n > FPB) n = FPB;
    const int n4 = n >> 2;

    for (int i = threadIdx.x; i < NBP; i += 256) hist[i] = 0u;
    __syncthreads();

    for (int j = threadIdx.x; j < n4; j += 256) {
        const int fb = f0 + 4 * j, e = 3 * fb;
        int4 va = *(const int4*)(vidx + e);
        int4 vb = *(const int4*)(vidx + e + 4);
        int4 vc = *(const int4*)(vidx + e + 8);
        float4 ea = *(const float4*)(ef + e);
        float4 eb = *(const float4*)(ef + e + 4);
        float4 ec = *(const float4*)(ef + e + 8);
        float4 a4 = *(const float4*)(afunc + fb);
        int   vv[12] = {va.x, va.y, va.z, va.w, vb.x, vb.y, vb.z, vb.w, vc.x, vc.y, vc.z, vc.w};
        float ss[12] = {ea.x, ea.y, ea.z, ea.w, eb.x, eb.y, eb.z, eb.w, ec.x, ec.y, ec.z, ec.w};
        float aa[4]  = {a4.x, a4.y, a4.z, a4.w};
        unsigned long long gq[4];
        #pragma unroll
        for (int q = 0; q < 4; ++q) {
            int v0 = vv[3 * q], v1 = vv[3 * q + 1], v2 = vv[3 * q + 2];
            unsigned int s0 = ss[3 * q]     > 0.0f ? 1u : 0u;
            unsigned int s1 = ss[3 * q + 1] > 0.0f ? 1u : 0u;
            unsigned int s2 = ss[3 * q + 2] > 0.0f ? 1u : 0u;
            unsigned int act = aa[q] != 0.0f ? 1u : 0u;
            gq[q] = (unsigned long long)(unsigned int)v0
                  | ((unsigned long long)(unsigned int)v1 << 20)
                  | ((unsigned long long)(unsigned int)v2 << 40)
                  | ((unsigned long long)s0 << 60)
                  | ((unsigned long long)s1 << 61)
                  | ((unsigned long long)s2 << 62)
                  | ((unsigned long long)act << 63);
            if (act) {
                atomicAdd(&hist[v0 >> BIN_BITS], 1u);
                atomicAdd(&hist[v1 >> BIN_BITS], 1u);
                atomicAdd(&hist[v2 >> BIN_BITS], 1u);
            }
        }
        *(ulonglong2*)(gpack + fb)     = make_ulonglong2(gq[0], gq[1]);
        *(ulonglong2*)(gpack + fb + 2) = make_ulonglong2(gq[2], gq[3]);
    }
    for (int i = 4 * n4 + threadIdx.x; i < n; i += 256) {
        const int f = f0 + i, e0 = 3 * f;
        int v0 = vidx[e0], v1 = vidx[e0 + 1], v2 = vidx[e0 + 2];
        unsigned int s0 = ef[e0]     > 0.0f ? 1u : 0u;
        unsigned int s1 = ef[e0 + 1] > 0.0f ? 1u : 0u;
        unsigned int s2 = ef[e0 + 2] > 0.0f ? 1u : 0u;
        unsigned int act = afunc[f] != 0.0f ? 1u : 0u;
        unsigned long long g = (unsigned long long)(unsigned int)v0
                             | ((unsigned long long)(unsigned int)v1 << 20)
                             | ((unsigned long long)(unsigned int)v2 << 40)
                             | ((unsigned long long)s0 << 60)
                             | ((unsigned long long)s1 << 61)
                             | ((unsigned long long)s2 << 62)
                             | ((unsigned long long)act << 63);
        gpack[f] = g;
        if (act) {
            atomicAdd(&hist[v0 >> BIN_BITS], 1u);
            atomicAdd(&hist[v1 >> BIN_BITS], 1u);
            atomicAdd(&hist[v2 >> BIN_BITS], 1u);
        }
    }
    __syncthreads();

    {
        const int t = threadIdx.x, lane = t & 63, wid = t >> 6;
        unsigned int a0 = hist[4 * t], a1 = hist[4 * t + 1];
        unsigned int a2 = hist[4 * t + 2], a3 = hist[4 * t + 3];
        unsigned int tsum = a0 + a1 + a2 + a3;
        unsigned int x = tsum;
        #pragma unroll
        for (int off = 1; off < 64; off <<= 1) {
            unsigned int y = (unsigned int)__shfl_up((int)x, off);
            if (lane >= off) x += y;
        }
        if (lane == 63) wsum[wid] = x;
        __syncthreads();
        unsigned int wbase = 0;
        for (int w = 0; w < wid; ++w) wbase += wsum[w];
        unsigned int e0x = wbase + x - tsum;
        unsigned int e1x = e0x + a0, e2x = e1x + a1, e3x = e2x + a2;
        cur[4 * t] = e0x; cur[4 * t + 1] = e1x; cur[4 * t + 2] = e2x; cur[4 * t + 3] = e3x;
        unsigned short* row = offs + (size_t)k * OROW;
        if (4 * t     <= NB) row[4 * t]     = (unsigned short)e0x;
        if (4 * t + 1 <= NB) row[4 * t + 1] = (unsigned short)e1x;
        if (4 * t + 2 <= NB) row[4 * t + 2] = (unsigned short)e2x;
        if (4 * t + 3 <= NB) row[4 * t + 3] = (unsigned short)e3x;
    }
    __syncthreads();

    const size_t rbase = (size_t)k * RSTRIDE;
    for (int j = threadIdx.x; j < n4; j += 256) {
        const int fb = f0 + 4 * j;
        ulonglong2 ga = *(const ulonglong2*)(gpack + fb);
        ulonglong2 gb = *(const ulonglong2*)(gpack + fb + 2);
        unsigned long long gq[4] = {ga.x, ga.y, gb.x, gb.y};
        #pragma unroll
        for (int q = 0; q < 4; ++q) {
            unsigned long long g = gq[q];
            if ((long long)g < 0) {
                unsigned int v0 = (unsigned int)(g & 0xFFFFFu);
                unsigned int v1 = (unsigned int)((g >> 20) & 0xFFFFFu);
                unsigned int v2 = (unsigned int)((g >> 40) & 0xFFFFFu);
                unsigned int sl0 = atomicAdd(&cur[v0 >> BIN_BITS], 1u);
                sorted[rbase + sl0] = (unsigned short)((v0 & (CH_SIZE - 1)) | ((unsigned int)((g >> 60) & 1u) << CH_BITS));
                unsigned int sl1 = atomicAdd(&cur[v1 >> BIN_BITS], 1u);
                sorted[rbase + sl1] = (unsigned short)((v1 & (CH_SIZE - 1)) | ((unsigned int)((g >> 61) & 1u) << CH_BITS));
                unsigned int sl2 = atomicAdd(&cur[v2 >> BIN_BITS], 1u);
                sorted[rbase + sl2] = (unsigned short)((v2 & (CH_SIZE - 1)) | ((unsigned int)((g >> 62) & 1u) << CH_BITS));
            }
        }
    }
    for (int i = 4 * n4 + threadIdx.x; i < n; i += 256) {
        unsigned long long g = gpack[f0 + i];
        if ((long long)g < 0) {
            unsigned int v0 = (unsigned int)(g & 0xFFFFFu);
            unsigned int v1 = (unsigned int)((g >> 20) & 0xFFFFFu);
            unsigned int v2 = (unsigned int)((g >> 40) & 0xFFFFFu);
            unsigned int sl0 = atomicAdd(&cur[v0 >> BIN_BITS], 1u);
            sorted[rbase + sl0] = (unsigned short)((v0 & (CH_SIZE - 1)) | ((unsigned int)((g >> 60) & 1u) << CH_BITS));
            unsigned int sl1 = atomicAdd(&cur[v1 >> BIN_BITS], 1u);
            sorted[rbase + sl1] = (unsigned short)((v1 & (CH_SIZE - 1)) | ((unsigned int)((g >> 61) & 1u) << CH_BITS));
            unsigned int sl2 = atomicAdd(&cur[v2 >> BIN_BITS], 1u);
            sorted[rbase + sl2] = (unsigned short)((v2 & (CH_SIZE - 1)) | ((unsigned int)((g >> 62) & 1u) << CH_BITS));
        }
    }
}

__global__ __launch_bounds__(1024) void k_accum(
    const unsigned short* __restrict__ offs_T,
    const unsigned short* __restrict__ sorted,
    const float* __restrict__ avars,
    unsigned int* __restrict__ packed,
    unsigned long long* __restrict__ avm,
    unsigned long long* __restrict__ svm,
    unsigned char* __restrict__ sgrp)
{
    __shared__ unsigned int acc[CH_SIZE];
    __shared__ unsigned short row0[SBLK];
    __shared__ unsigned short row1[SBLK];
    const int c = blockIdx.x;
    const int r0 = 4 * c;
    const int r1 = (4 * c + 4 < NB) ? (4 * c + 4) : NB;
    for (int i = threadIdx.x; i < CH_SIZE; i += 1024) acc[i] = 0u;
    for (int i = threadIdx.x; i < SBLK; i += 1024) {
        row0[i] = offs_T[(size_t)r0 * SBLK + i];
        row1[i] = offs_T[(size_t)r1 * SBLK + i];
    }
    __syncthreads();
    for (int k = threadIdx.x; k < SBLK; k += 1024) {
        const int s0 = row0[k], s1 = row1[k];
        const unsigned short* seg = sorted + (size_t)k * RSTRIDE;
        for (int e = s0; e < s1; ++e) {
            unsigned int p = seg[e];
            atomicAdd(&acc[p & (CH_SIZE - 1)], 0x10000u | (p >> CH_BITS));
        }
    }
    __syncthreads();
    const int vbase = c << CH_BITS;
    for (int i = threadIdx.x; i < CH_SIZE; i += 1024) {
        int v = vbase + i;
        bool valid = v < Vn;
        unsigned int p = valid ? acc[i] : 0u;
        bool av = valid && (avars[v] != 0.0f);
        unsigned int cnt = p >> 16, pos = p & 0xFFFFu;
        bool sv = av && (pos == 0u || pos == cnt);
        unsigned long long avb = __ballot(av);
        unsigned long long svb = __ballot(sv);
        if (valid) packed[v] = p;
        if ((threadIdx.x & 63) == 0) {
            avm[v >> 6] = avb;
            svm[v >> 6] = svb;
            sgrp[v >> 6] = (svb != 0ull) ? 1 : 0;
        }
    }
}

__global__ void k_zero_tmp(unsigned int* __restrict__ tmp, unsigned char* __restrict__ tgrp) {
    int v = blockIdx.x * blockDim.x + threadIdx.x;
    if (v < Vn) tmp[v] = 0u;
    if (v < AVW) tgrp[v] = 0;
}

__device__ __forceinline__ void fire_one(unsigned long long g, int f,
                                         unsigned long long* __restrict__ gpack,
                                         const unsigned int* __restrict__ svm32,
                                         const unsigned char* __restrict__ sgrp,
                                         unsigned int* __restrict__ tmp,
                                         unsigned char* __restrict__ tgrp)
{
    if ((long long)g >= 0) return;
    unsigned int v0 = (unsigned int)(g & 0xFFFFFu);
    unsigned int v1 = (unsigned int)((g >> 20) & 0xFFFFFu);
    unsigned int v2 = (unsigned int)((g >> 40) & 0xFFFFFu);
    if (!(sgrp[v0 >> 6] | sgrp[v1 >> 6] | sgrp[v2 >> 6])) return;
    unsigned int hit = ((svm32[v0 >> 5] >> (v0 & 31u)) |
                        (svm32[v1 >> 5] >> (v1 & 31u)) |
                        (svm32[v2 >> 5] >> (v2 & 31u))) & 1u;
    if (!hit) return;
    gpack[f] = g & ~(1ull << 63);
    atomicAdd(&tmp[v0], 0x10000u | (unsigned int)((g >> 60) & 1u));
    atomicAdd(&tmp[v1], 0x10000u | (unsigned int)((g >> 61) & 1u));
    atomicAdd(&tmp[v2], 0x10000u | (unsigned int)((g >> 62) & 1u));
    tgrp[v0 >> 6] = 1; tgrp[v1 >> 6] = 1; tgrp[v2 >> 6] = 1;
}

__global__ void k_funcs(unsigned long long* __restrict__ gpack,
                        const unsigned int* __restrict__ svm32,
                        const unsigned char* __restrict__ sgrp,
                        unsigned int* __restrict__ tmp,
                        unsigned char* __restrict__ tgrp)
{
    int gid = blockIdx.x * blockDim.x + threadIdx.x;
    int f = 2 * gid;
    if (f >= Fn) return;
    ulonglong2 g2 = *(const ulonglong2*)(gpack + f);
    fire_one(g2.x, f,     gpack, svm32, sgrp, tmp, tgrp);
    fire_one(g2.y, f + 1, gpack, svm32, sgrp, tmp, tgrp);
}

__global__ void k_update(unsigned int* __restrict__ packed,
                         unsigned int* __restrict__ tmp,
                         unsigned long long* __restrict__ avm,
                         unsigned long long* __restrict__ svm,
                         unsigned char* __restrict__ sgrp,
                         unsigned char* __restrict__ tgrp,
                         float* __restrict__ deg, int write_deg)
{
    int v = blockIdx.x * blockDim.x + threadIdx.x;
    int lane = threadIdx.x & 63;
    bool valid = v < Vn;
    unsigned long long avw = 0ull, svw = 0ull;
    unsigned char tg = 0;
    if (valid) {
        avw = avm[v >> 6]; svw = svm[v >> 6];
        tg = tgrp[v >> 6];
    }
    bool av_old = valid && ((avw >> lane) & 1ull);
    bool sv     = valid && ((svw >> lane) & 1ull);
    bool av_new = av_old && !sv;
    unsigned int p = 0u;
    if (valid) {
        p = packed[v];
        if (tg) {
            unsigned int tp = tmp[v];
            if (tp != 0u) {
                if (av_old) { p -= tp; packed[v] = p; }
                tmp[v] = 0u;
            }
        }
    }
    unsigned int c = p >> 16, pos = p & 0xFFFFu;
    bool nsv = av_new && (pos == 0u || pos == c);
    unsigned long long nsvb = __ballot(nsv);
    if (lane == 0 && valid) {
        svm[v >> 6] = nsvb;
        avm[v >> 6] = avw & ~svw;
        sgrp[v >> 6] = (nsvb != 0ull) ? 1 : 0;
        if (tg) tgrp[v >> 6] = 0;
    }
    if (write_deg && valid) deg[v] = (float)c;
}

// ======================= launcher =======================
extern "C" void kernel_launch(void* const* d_in, const int* in_sizes, int n_in,
                              void* d_out, int out_size, void* d_ws, size_t ws_size,
                              hipStream_t stream) {
    const int*   graph_map        = (const int*)d_in[0];
    const float* edge_feature     = (const float*)d_in[1];
    const float* active_variables = (const float*)d_in[2];
    const float* active_functions = (const float*)d_in[3];
    const int* vidx = graph_map;
    float* deg = (float*)d_out;
    char* ws = (char*)d_ws;

    const int BS = 256;
    const int gV = (Vn + BS - 1) / BS;
    const int gF = (Fn + BS - 1) / BS;

    // ---- CSR-path workspace requirement (<= R11's proven NEED) ----
    const size_t szA   = 4ull * SBLK * RSTRIDE;       // u32 regions (alias frontB/touched after build)
    const size_t szOfs = 2ull * SBLK * OROW;          // offs (row_start aliases after transpose)
    const size_t szOfT = 2ull * SBLK * OROW;          // offs_T (eclaim aliases after build)
    const size_t szC   = 4ull * NCH * CH_SIZE;        // packed (padded)
    const size_t szCsr = 4ull * NB * CAP_BIN;         // csr, fixed per-bin capacity
    const size_t szF   = 1ull * NCH * CH_SIZE;        // cnt8
    const size_t szFep = 4ull * Vn;
    const size_t szAv8 = 1ull * NCH * CH_SIZE;
    const size_t szFrA = 4ull * Vn;
    const size_t szFm  = 4ull * ((FWORDS + 127) & ~127);
    const size_t szMisc = 65536;
    const size_t NEED = szA + szOfs + szOfT + szC + szCsr + szF + szFep + szAv8 + szFrA + szFm + szMisc;

    if (ws_size >= NEED) {
        // ================= CSR / frontier path =================
        size_t off = 0;
        unsigned int* regions32 = (unsigned int*)(ws + off); off += szA;
        unsigned int* frontB  = (unsigned int*)((char*)regions32);                // 4 MB (dead sorted)
        unsigned int* touched = (unsigned int*)((char*)regions32 + 4ull * Vn);    // 32 MB (dead sorted)
        unsigned short* offs   = (unsigned short*)(ws + off); off += szOfs;
        unsigned int* row_start = (unsigned int*)offs;        // alias (offs dead after transpose)
        unsigned short* offs_T = (unsigned short*)(ws + off); off += szOfT;
        unsigned int* eclaim = (unsigned int*)offs_T;         // alias (dead after build; zeroed in funcs_0)
        unsigned int* packed   = (unsigned int*)(ws + off); off += szC;
        unsigned int* csr      = (unsigned int*)(ws + off); off += szCsr;
        unsigned char* cnt8     = (unsigned char*)(ws + off); off += szF;
        unsigned int* fep       = (unsigned int*)(ws + off); off += szFep;
        unsigned char* av8      = (unsigned char*)(ws + off); off += szAv8;
        unsigned int* frontA    = (unsigned int*)(ws + off); off += szFrA;
        unsigned int* fmask     = (unsigned int*)(ws + off); off += szFm;
        unsigned int* counters  = (unsigned int*)(ws + off); off += 4096;

        kc_init<<<gF, BS, 0, stream>>>(active_functions, fmask, fep, counters);
        kc_pack_sort<<<SBLK, 256, 0, stream>>>(vidx, edge_feature, active_functions, offs, regions32);
        k_transpose<<<dim3(OROW / 64, SBLK / 64), 256, 0, stream>>>(offs, offs_T);
        kc_build<<<248, 1024, 0, stream>>>(offs_T, regions32, active_variables, packed,
                                           av8, cnt8, row_start, csr, frontA, counters, fep);
        for (int t = 0; t < Tn; ++t) {
            const unsigned int* fcur = (t & 1) ? frontB : frontA;
            unsigned int* fnext = (t & 1) ? frontA : frontB;
            kc_funcs<<<256, 256, 0, stream>>>(csr, row_start, cnt8, fmask, vidx, edge_feature,
                                              packed, av8, touched, counters, fcur, eclaim, t);
            if (t < Tn - 1)
                kc_update<<<256, 256, 0, stream>>>(packed, av8, fep, eclaim, touched,
                                                   fcur, fnext, counters, t);
        }
        kc_out<<<gV, BS, 0, stream>>>(packed, deg);
    } else {
        // ================= R8 fallback path =================
        size_t off = 0;
        unsigned long long* gpack = (unsigned long long*)(ws + off); off += 8ull * Fn;
        unsigned int* packed      = (unsigned int*)(ws + off);       off += 4ull * Vn;
        unsigned long long* avm   = (unsigned long long*)(ws + off); off += 8ull * AVW;
        unsigned long long* svm   = (unsigned long long*)(ws + off); off += 8ull * AVW;
        unsigned char* sgrp       = (unsigned char*)(ws + off);      off += (size_t)((AVW + 255) & ~255);
        unsigned char* tgrp       = (unsigned char*)(ws + off);      off += (size_t)((AVW + 255) & ~255);
        unsigned short* offs      = (unsigned short*)(ws + off);     off += 2ull * SBLK * OROW;
        unsigned short* offs_T    = (unsigned short*)(ws + off);     off += 2ull * SBLK * OROW;
        unsigned short* sorted    = (unsigned short*)(ws + off);     off += 2ull * SBLK * RSTRIDE;
        unsigned int* tmp = (unsigned int*)sorted;

        const int gF2 = (Fn / 2 + BS - 1) / BS;
        k_pack_sort<<<SBLK, 256, 0, stream>>>(vidx, edge_feature, active_functions, gpack, offs, sorted);
        k_transpose<<<dim3(OROW / 64, SBLK / 64), 256, 0, stream>>>(offs, offs_T);
        k_accum<<<NCH, 1024, 0, stream>>>(offs_T, sorted, active_variables, packed, avm, svm, sgrp);
        k_zero_tmp<<<gV, BS, 0, stream>>>(tmp, tgrp);
        for (int t = 0; t < Tn; ++t) {
            k_funcs<<<gF2, BS, 0, stream>>>(gpack, (const unsigned int*)svm, sgrp, tmp, tgrp);
            k_update<<<gV, BS, 0, stream>>>(packed, tmp, avm, svm, sgrp, tgrp, deg, (t == Tn - 1) ? 1 : 0);
        }
    }
}

// Round 13
// 508.266 us; speedup vs baseline: 1.5834x; 1.0767x over previous
//
#include <hip/hip_runtime.h>

// Peeling propagation on bipartite graph. V=1e6, F=4.2e6, K=3 (edge e -> function e/3).
// T=5. Output: deg (V floats) in d_out.
//
// R13 (CSR/frontier path, ws-gated; fallback = R8 verbatim):
//  * kc_build: SINGLE global span walk. R12 walked every span twice (FETCH 214MB,
//    fetch-bound at 172us). Pass A now stages raw entries in LDS (register-computed
//    per-region bases from an LDS span-length scan) while accumulating; pass B
//    reorders stageRaw->stageOut entirely in LDS; csr written as one coalesced
//    stream. LDS ~136KB -> 1 block/CU (grid 248 was already ~1/CU; no loss).
//  * kc_pack_sort: reverted to R9's proven gpack-staged two-pass (~97us in R8);
//    gpack staging aliases the csr buffer (dead before kc_build) -> no ws growth.

static constexpr int Vn = 1000000;
static constexpr int Fn = 4200000;
static constexpr int En = 3 * Fn;                          // 12.6M edges
static constexpr int Tn = 5;

static constexpr int SBLK = 2048;                          // sort blocks / regions
static constexpr int FPB  = 2052;                          // functions/block (mult of 4)
static constexpr int BIN_BITS = 10;                        // fine bin = 1024 vars
static constexpr int BIN_SIZE = 1 << BIN_BITS;
static constexpr int NB  = (Vn + BIN_SIZE - 1) >> BIN_BITS;   // 977 fine bins
static constexpr int NBP = 1024;
static constexpr int CH_BITS = 12;                         // chunk = 4096 vars
static constexpr int CH_SIZE = 1 << CH_BITS;
static constexpr int NCH = (Vn + CH_SIZE - 1) >> CH_BITS;  // 245 chunks
static constexpr int RCAP = 3 * FPB;
static constexpr int RSTRIDE = (RCAP + 63) & ~63;          // 6208
static constexpr int OROW = 1024;
static constexpr int AVW = NCH * (CH_SIZE / 64);           // R8 mask words
static constexpr unsigned int TCAP = 8u * 1024u * 1024u;   // touched-list capacity
static constexpr int FWORDS = Fn / 32;                     // 131250 fmask words
static constexpr unsigned int CAP_BIN = 13888;             // fixed csr entries/bin (exp 12897, +8.7sigma)

// ======================= shared: transpose =======================
__global__ __launch_bounds__(256) void k_transpose(const unsigned short* __restrict__ in,
                                                   unsigned short* __restrict__ out) {
    __shared__ unsigned short t[64][65];
    const int bx = blockIdx.x, by = blockIdx.y;
    for (int i = threadIdx.x; i < 64 * 64; i += 256) {
        int r = i >> 6, c = i & 63;
        t[r][c] = in[(size_t)(by * 64 + r) * OROW + (bx * 64 + c)];
    }
    __syncthreads();
    for (int i = threadIdx.x; i < 64 * 64; i += 256) {
        int r = i >> 6, c = i & 63;
        out[(size_t)(bx * 64 + r) * SBLK + (by * 64 + c)] = t[c][r];
    }
}

// ======================= CSR-path kernels =======================

// fused init: fmask ballots + zero fep + zero counters
__global__ void kc_init(const float* __restrict__ afunc, unsigned int* __restrict__ fmask,
                        unsigned int* __restrict__ fep, unsigned int* __restrict__ counters) {
    int f = blockIdx.x * blockDim.x + threadIdx.x;
    bool act = (f < Fn) && (afunc[f] != 0.0f);
    unsigned long long b = __ballot(act);
    int lane = threadIdx.x & 63;
    if (f < Fn) {
        int w = f >> 5;
        if (lane == 0)  fmask[w] = (unsigned int)b;
        if (lane == 32) fmask[w] = (unsigned int)(b >> 32);
    }
    if (f < Vn) fep[f] = 0u;
    if (f < 64) counters[f] = 0u;
}

// pack + hist + scan + scatter; gpack staging (aliased into csr buf, L2-hot re-read).
// sorted entry (u32): v_local12 | sign<<12 | fid_rel<<13   [R9-proven structure]
__global__ __launch_bounds__(256) void kc_pack_sort(
    const int* __restrict__ vidx, const float* __restrict__ ef,
    const float* __restrict__ afunc,
    unsigned long long* __restrict__ gpack,
    unsigned short* __restrict__ offs,
    unsigned int* __restrict__ sorted)
{
    __shared__ unsigned int hist[NBP];
    __shared__ unsigned int cur[NBP];
    __shared__ unsigned int wsum[4];

    const int k = blockIdx.x;
    const int f0 = k * FPB;
    int n = Fn - f0; if (n < 0) n = 0; if (n > FPB) n = FPB;
    const int n4 = n >> 2;

    for (int i = threadIdx.x; i < NBP; i += 256) hist[i] = 0u;
    __syncthreads();

    for (int j = threadIdx.x; j < n4; j += 256) {
        const int fb = f0 + 4 * j, e = 3 * fb;
        int4 va = *(const int4*)(vidx + e);
        int4 vb = *(const int4*)(vidx + e + 4);
        int4 vc = *(const int4*)(vidx + e + 8);
        float4 ea = *(const float4*)(ef + e);
        float4 eb = *(const float4*)(ef + e + 4);
        float4 ec = *(const float4*)(ef + e + 8);
        float4 a4 = *(const float4*)(afunc + fb);
        int   vv[12] = {va.x, va.y, va.z, va.w, vb.x, vb.y, vb.z, vb.w, vc.x, vc.y, vc.z, vc.w};
        float ss[12] = {ea.x, ea.y, ea.z, ea.w, eb.x, eb.y, eb.z, eb.w, ec.x, ec.y, ec.z, ec.w};
        float aa[4]  = {a4.x, a4.y, a4.z, a4.w};
        unsigned long long gq[4];
        #pragma unroll
        for (int q = 0; q < 4; ++q) {
            int v0 = vv[3 * q], v1 = vv[3 * q + 1], v2 = vv[3 * q + 2];
            unsigned int s0 = ss[3 * q]     > 0.0f ? 1u : 0u;
            unsigned int s1 = ss[3 * q + 1] > 0.0f ? 1u : 0u;
            unsigned int s2 = ss[3 * q + 2] > 0.0f ? 1u : 0u;
            unsigned int act = aa[q] != 0.0f ? 1u : 0u;
            gq[q] = (unsigned long long)(unsigned int)v0
                  | ((unsigned long long)(unsigned int)v1 << 20)
                  | ((unsigned long long)(unsigned int)v2 << 40)
                  | ((unsigned long long)s0 << 60)
                  | ((unsigned long long)s1 << 61)
                  | ((unsigned long long)s2 << 62)
                  | ((unsigned long long)act << 63);
            if (act) {
                atomicAdd(&hist[v0 >> BIN_BITS], 1u);
                atomicAdd(&hist[v1 >> BIN_BITS], 1u);
                atomicAdd(&hist[v2 >> BIN_BITS], 1u);
            }
        }
        *(ulonglong2*)(gpack + fb)     = make_ulonglong2(gq[0], gq[1]);
        *(ulonglong2*)(gpack + fb + 2) = make_ulonglong2(gq[2], gq[3]);
    }
    __syncthreads();

    // shuffle-based exclusive scan over 1024 fine bins
    {
        const int t = threadIdx.x, lane = t & 63, wid = t >> 6;
        unsigned int a0 = hist[4 * t], a1 = hist[4 * t + 1];
        unsigned int a2 = hist[4 * t + 2], a3 = hist[4 * t + 3];
        unsigned int tsum = a0 + a1 + a2 + a3;
        unsigned int x = tsum;
        #pragma unroll
        for (int off = 1; off < 64; off <<= 1) {
            unsigned int y = (unsigned int)__shfl_up((int)x, off);
            if (lane >= off) x += y;
        }
        if (lane == 63) wsum[wid] = x;
        __syncthreads();
        unsigned int wbase = 0;
        for (int w = 0; w < wid; ++w) wbase += wsum[w];
        unsigned int e0x = wbase + x - tsum;
        unsigned int e1x = e0x + a0, e2x = e1x + a1, e3x = e2x + a2;
        cur[4 * t] = e0x; cur[4 * t + 1] = e1x; cur[4 * t + 2] = e2x; cur[4 * t + 3] = e3x;
        unsigned short* row = offs + (size_t)k * OROW;
        if (4 * t     <= NB) row[4 * t]     = (unsigned short)e0x;
        if (4 * t + 1 <= NB) row[4 * t + 1] = (unsigned short)e1x;
        if (4 * t + 2 <= NB) row[4 * t + 2] = (unsigned short)e2x;
        if (4 * t + 3 <= NB) row[4 * t + 3] = (unsigned short)e3x;
    }
    __syncthreads();

    // pass 2: re-read gpack (L2-hot) and scatter u32 entries
    const size_t rbase = (size_t)k * RSTRIDE;
    for (int j = threadIdx.x; j < n4; j += 256) {
        const int fb = f0 + 4 * j;
        ulonglong2 ga = *(const ulonglong2*)(gpack + fb);
        ulonglong2 gb = *(const ulonglong2*)(gpack + fb + 2);
        unsigned long long gq[4] = {ga.x, ga.y, gb.x, gb.y};
        #pragma unroll
        for (int q = 0; q < 4; ++q) {
            unsigned long long g = gq[q];
            if ((long long)g < 0) {
                unsigned int fr = (unsigned int)(4 * j + q) << 13;
                unsigned int v0 = (unsigned int)(g & 0xFFFFFu);
                unsigned int v1 = (unsigned int)((g >> 20) & 0xFFFFFu);
                unsigned int v2 = (unsigned int)((g >> 40) & 0xFFFFFu);
                unsigned int sl0 = atomicAdd(&cur[v0 >> BIN_BITS], 1u);
                sorted[rbase + sl0] = (v0 & (CH_SIZE - 1)) | ((unsigned int)((g >> 60) & 1u) << 12) | fr;
                unsigned int sl1 = atomicAdd(&cur[v1 >> BIN_BITS], 1u);
                sorted[rbase + sl1] = (v1 & (CH_SIZE - 1)) | ((unsigned int)((g >> 61) & 1u) << 12) | fr;
                unsigned int sl2 = atomicAdd(&cur[v2 >> BIN_BITS], 1u);
                sorted[rbase + sl2] = (v2 & (CH_SIZE - 1)) | ((unsigned int)((g >> 62) & 1u) << 12) | fr;
            }
        }
    }
}

// merged accumulate + CSR build, SINGLE global span walk.
// Per chunk (XCD-swizzled), 4 bin phases: span-length scan -> register bases;
// pass A: read spans once, stage raw entries in LDS + accumulate counts;
// count scan -> per-var outputs; pass B: LDS-only reorder stageRaw->stageOut;
// coalesced csr segment write.
__global__ __launch_bounds__(1024) void kc_build(
    const unsigned short* __restrict__ offs_T,
    const unsigned int* __restrict__ sorted,
    const float* __restrict__ avars,
    unsigned int* __restrict__ packed,
    unsigned char* __restrict__ av8,
    unsigned char* __restrict__ cnt8,
    unsigned int* __restrict__ row_start,
    unsigned int* __restrict__ csr,
    unsigned int* __restrict__ frontA,
    unsigned int* __restrict__ counters,
    unsigned int* __restrict__ fep)
{
    __shared__ unsigned int stageRaw[CAP_BIN];   // 55,552 B
    __shared__ unsigned int stageOut[CAP_BIN];   // 55,552 B
    __shared__ unsigned int acc[BIN_SIZE];       // 4 KB (accumulate, then cursor)
    __shared__ unsigned short rows[5][SBLK];     // 20,480 B
    __shared__ unsigned int wsum2[16];
    __shared__ unsigned int sh_total;
    // total ~136 KB -> 1 block/CU (grid 248 was ~1/CU anyway)

    const int bid = blockIdx.x;
    const int c = (bid & 7) * 31 + (bid >> 3);   // XCD swizzle: 31 consecutive chunks/XCD
    if (c >= NCH) return;

    for (int r = 0; r < 5; ++r) {
        int rr = 4 * c + r; if (rr > NB) rr = NB;
        for (int i = threadIdx.x; i < SBLK; i += 1024)
            rows[r][i] = offs_T[(size_t)rr * SBLK + i];
    }
    const int t = threadIdx.x, lane = t & 63, wid = t >> 6;
    const int k0 = 2 * t, k1 = 2 * t + 1;        // this thread's two regions

    #pragma unroll 1
    for (int ph = 0; ph < 4; ++ph) {
        const int b = 4 * c + ph;
        if (b >= NB) break;
        acc[t] = 0u;
        // span-length scan -> register bases for this thread's regions
        const int s0 = rows[ph][k0], e0s = rows[ph + 1][k0];
        const int s1 = rows[ph][k1], e1s = rows[ph + 1][k1];
        const unsigned int len0 = (unsigned int)(e0s - s0);
        const unsigned int len1 = (unsigned int)(e1s - s1);
        const unsigned int pair = len0 + len1;
        unsigned int x = pair;
        #pragma unroll
        for (int off = 1; off < 64; off <<= 1) {
            unsigned int y = (unsigned int)__shfl_up((int)x, off);
            if (lane >= off) x += y;
        }
        if (lane == 63) wsum2[wid] = x;
        __syncthreads();
        unsigned int wbase = 0;
        for (int w = 0; w < wid; ++w) wbase += wsum2[w];
        unsigned int base0 = wbase + x - pair;
        unsigned int base1 = base0 + len0;
        if (t == 1023) sh_total = base0 + pair;
        __syncthreads();                          // acc zero + wsum2 reads complete

        // pass A: read spans ONCE, stage raw + accumulate
        {
            const unsigned int* seg = sorted + (size_t)k0 * RSTRIDE;
            unsigned int w0 = base0;
            for (int e = s0; e < e0s; ++e, ++w0) {
                unsigned int p = seg[e];
                if (w0 < CAP_BIN) stageRaw[w0] = p;
                atomicAdd(&acc[p & (BIN_SIZE - 1)], 0x10000u | ((p >> 12) & 1u));
            }
            const unsigned int* seg2 = sorted + (size_t)k1 * RSTRIDE;
            unsigned int w1 = base1;
            for (int e = s1; e < e1s; ++e, ++w1) {
                unsigned int p = seg2[e];
                if (w1 < CAP_BIN) stageRaw[w1] = p;
                atomicAdd(&acc[p & (BIN_SIZE - 1)], 0x10000u | ((p >> 12) & 1u));
            }
        }
        __syncthreads();

        // count scan -> exclusive prefix; per-var outputs
        unsigned int pk = acc[t];
        unsigned int cnt = pk >> 16, pos = pk & 0xFFFFu;
        unsigned int xc = cnt;
        #pragma unroll
        for (int off = 1; off < 64; off <<= 1) {
            unsigned int y = (unsigned int)__shfl_up((int)xc, off);
            if (lane >= off) xc += y;
        }
        if (lane == 63) wsum2[wid] = xc;
        __syncthreads();
        unsigned int wbase2 = 0;
        for (int w = 0; w < wid; ++w) wbase2 += wsum2[w];
        const unsigned int e0 = wbase2 + xc - cnt;
        const int v = (b << BIN_BITS) + t;
        if (v < Vn) {
            packed[v] = pk;
            bool av = avars[v] != 0.0f;
            av8[v] = av ? 1 : 0;
            cnt8[v] = (unsigned char)(cnt > 255u ? 255u : cnt);
            row_start[v] = (unsigned int)b * CAP_BIN + e0;
            if (av && (pos == 0u || pos == cnt)) {          // initial single_v
                unsigned int ix = atomicAdd(&counters[0], 1u);
                frontA[ix] = (unsigned int)v;
                fep[v] = 1u;
            }
        }
        __syncthreads();
        acc[t] = e0;                                        // cursor for pass B
        __syncthreads();

        // pass B: LDS-only reorder stageRaw -> stageOut
        {
            const unsigned int fb0 = (unsigned int)k0 * (unsigned int)FPB;
            unsigned int r0p = base0;
            for (unsigned int j = 0; j < len0 && r0p < CAP_BIN; ++j, ++r0p) {
                unsigned int p = stageRaw[r0p];
                unsigned int slot = atomicAdd(&acc[p & (BIN_SIZE - 1)], 1u);
                if (slot < CAP_BIN)
                    stageOut[slot] = ((fb0 + (p >> 13)) << 1) | ((p >> 12) & 1u);
            }
            const unsigned int fb1 = (unsigned int)k1 * (unsigned int)FPB;
            unsigned int r1p = base1;
            for (unsigned int j = 0; j < len1 && r1p < CAP_BIN; ++j, ++r1p) {
                unsigned int p = stageRaw[r1p];
                unsigned int slot = atomicAdd(&acc[p & (BIN_SIZE - 1)], 1u);
                if (slot < CAP_BIN)
                    stageOut[slot] = ((fb1 + (p >> 13)) << 1) | ((p >> 12) & 1u);
            }
        }
        __syncthreads();
        unsigned int total = sh_total;
        if (total > CAP_BIN) total = CAP_BIN;
        for (unsigned int i = t; i < total; i += 1024)
            csr[(size_t)b * CAP_BIN + i] = stageOut[i];
        __syncthreads();
    }
}

// frontier walk: claim adjacent active functions; av-gated DIRECT decrement of packed;
// push touched. t==0 also zeroes eclaim (aliases dead offs_T).
__global__ void kc_funcs(const unsigned int* __restrict__ csr,
                         const unsigned int* __restrict__ row_start,
                         const unsigned char* __restrict__ cnt8,
                         unsigned int* __restrict__ fmask,
                         const int* __restrict__ vidx, const float* __restrict__ ef,
                         unsigned int* __restrict__ packed,
                         const unsigned char* __restrict__ av8,
                         unsigned int* __restrict__ touched,
                         unsigned int* __restrict__ counters,
                         const unsigned int* __restrict__ frontier,
                         unsigned int* __restrict__ eclaim, int t)
{
    const int gid = blockIdx.x * blockDim.x + threadIdx.x;
    const int gsz = gridDim.x * blockDim.x;
    if (t == 0) {
        for (int v = gid; v < Vn; v += gsz) eclaim[v] = 0u;
    }
    const unsigned int fcnt = counters[t];
    for (unsigned int i = gid; i < fcnt; i += gsz) {
        unsigned int v = frontier[i];
        unsigned int rs = row_start[v];
        unsigned int re = rs + cnt8[v];
        for (unsigned int j = rs; j < re; ++j) {
            unsigned int f = csr[j] >> 1;
            unsigned int w = f >> 5, m = 1u << (f & 31u);
            unsigned int old = atomicAnd(&fmask[w], ~m);
            if (old & m) {
                int e0 = 3 * (int)f;
                int a0 = vidx[e0], a1 = vidx[e0 + 1], a2 = vidx[e0 + 2];
                unsigned int s0 = ef[e0]     > 0.0f ? 1u : 0u;
                unsigned int s1 = ef[e0 + 1] > 0.0f ? 1u : 0u;
                unsigned int s2 = ef[e0 + 2] > 0.0f ? 1u : 0u;
                if (av8[a0]) atomicSub(&packed[a0], 0x10000u | s0);   // deg -= av-gated
                if (av8[a1]) atomicSub(&packed[a1], 0x10000u | s1);
                if (av8[a2]) atomicSub(&packed[a2], 0x10000u | s2);
                unsigned int bofs = atomicAdd(&counters[8 + t], 3u);
                if (bofs + 3u <= TCAP) {
                    touched[bofs] = (unsigned int)a0;
                    touched[bofs + 1] = (unsigned int)a1;
                    touched[bofs + 2] = (unsigned int)a2;
                }
            }
        }
    }
}

// sparse update: dedup (eclaim epoch); frontier vars deactivate; touched active vars
// tested for new-single -> next frontier. packed read-only here.
__global__ void kc_update(const unsigned int* __restrict__ packed,
                          unsigned char* __restrict__ av8,
                          unsigned int* __restrict__ fep,
                          unsigned int* __restrict__ eclaim,
                          const unsigned int* __restrict__ touched,
                          const unsigned int* __restrict__ frontier_cur,
                          unsigned int* __restrict__ frontier_next,
                          unsigned int* __restrict__ counters, int t)
{
    const int gid = blockIdx.x * blockDim.x + threadIdx.x;
    const int gsz = gridDim.x * blockDim.x;
    const unsigned int fcnt = counters[t];
    unsigned int tc = counters[8 + t];
    const unsigned int tcnt = tc > TCAP ? TCAP : tc;
    const unsigned int total = fcnt + tcnt;
    const unsigned int epoch = (unsigned int)(t + 1);
    for (unsigned int i = gid; i < total; i += gsz) {
        unsigned int v = (i < fcnt) ? frontier_cur[i] : touched[i - fcnt];
        if (atomicExch(&eclaim[v], epoch) == epoch) continue;   // dedup within iteration
        if (fep[v] == epoch) { av8[v] = 0; continue; }          // was single -> deactivate
        if (av8[v]) {
            unsigned int p = packed[v];
            unsigned int cnt = p >> 16, pos = p & 0xFFFFu;
            if (pos == 0u || pos == cnt) {
                unsigned int ix = atomicAdd(&counters[t + 1], 1u);
                frontier_next[ix] = v;
                fep[v] = epoch + 1u;
            }
        }
    }
}

__global__ void kc_out(const unsigned int* __restrict__ packed, float* __restrict__ deg) {
    int v = blockIdx.x * blockDim.x + threadIdx.x;
    if (v < Vn) deg[v] = (float)(packed[v] >> 16);
}

// ======================= R8 fallback kernels (verbatim) =======================

__global__ __launch_bounds__(256) void k_pack_sort(
    const int* __restrict__ vidx, const float* __restrict__ ef,
    const float* __restrict__ afunc,
    unsigned long long* __restrict__ gpack,
    unsigned short* __restrict__ offs,
    unsigned short* __restrict__ sorted)
{
    __shared__ unsigned int hist[NBP];
    __shared__ unsigned int cur[NBP];
    __shared__ unsigned int wsum[4];

    const int k = blockIdx.x;
    const int f0 = k * FPB;
    int n = Fn - f0; if (n < 0) n = 0; if (n > FPB) n = FPB;
    const int n4 = n >> 2;

    for (int i = threadIdx.x; i < NBP; i += 256) hist[i] = 0u;
    __syncthreads();

    for (int j = threadIdx.x; j < n4; j += 256) {
        const int fb = f0 + 4 * j, e = 3 * fb;
        int4 va = *(const int4*)(vidx + e);
        int4 vb = *(const int4*)(vidx + e + 4);
        int4 vc = *(const int4*)(vidx + e + 8);
        float4 ea = *(const float4*)(ef + e);
        float4 eb = *(const float4*)(ef + e + 4);
        float4 ec = *(const float4*)(ef + e + 8);
        float4 a4 = *(const float4*)(afunc + fb);
        int   vv[12] = {va.x, va.y, va.z, va.w, vb.x, vb.y, vb.z, vb.w, vc.x, vc.y, vc.z, vc.w};
        float ss[12] = {ea.x, ea.y, ea.z, ea.w, eb.x, eb.y, eb.z, eb.w, ec.x, ec.y, ec.z, ec.w};
        float aa[4]  = {a4.x, a4.y, a4.z, a4.w};
        unsigned long long gq[4];
        #pragma unroll
        for (int q = 0; q < 4; ++q) {
            int v0 = vv[3 * q], v1 = vv[3 * q + 1], v2 = vv[3 * q + 2];
            unsigned int s0 = ss[3 * q]     > 0.0f ? 1u : 0u;
            unsigned int s1 = ss[3 * q + 1] > 0.0f ? 1u : 0u;
            unsigned int s2 = ss[3 * q + 2] > 0.0f ? 1u : 0u;
            unsigned int act = aa[q] != 0.0f ? 1u : 0u;
            gq[q] = (unsigned long long)(unsigned int)v0
                  | ((unsigned long long)(unsigned int)v1 << 20)
                  | ((unsigned long long)(unsigned int)v2 << 40)
                  | ((unsigned long long)s0 << 60)
                  | ((unsigned long long)s1 << 61)
                  | ((unsigned long long)s2 << 62)
                  | ((unsigned long long)act << 63);
            if (act) {
                atomicAdd(&hist[v0 >> BIN_BITS], 1u);
                atomicAdd(&hist[v1 >> BIN_BITS], 1u);
                atomicAdd(&hist[v2 >> BIN_BITS], 1u);
            }
        }
        *(ulonglong2*)(gpack + fb)     = make_ulonglong2(gq[0], gq[1]);
        *(ulonglong2*)(gpack + fb + 2) = make_ulonglong2(gq[2], gq[3]);
    }
    for (int i = 4 * n4 + threadIdx.x; i < n; i += 256) {
        const int f = f0 + i, e0 = 3 * f;
        int v0 = vidx[e0], v1 = vidx[e0 + 1], v2 = vidx[e0 + 2];
        unsigned int s0 = ef[e0]     > 0.0f ? 1u : 0u;
        unsigned int s1 = ef[e0 + 1] > 0.0f ? 1u : 0u;
        unsigned int s2 = ef[e0 + 2] > 0.0f ? 1u : 0u;
        unsigned int act = afunc[f] != 0.0f ? 1u : 0u;
        unsigned long long g = (unsigned long long)(unsigned int)v0
                             | ((unsigned long long)(unsigned int)v1 << 20)
                             | ((unsigned long long)(unsigned int)v2 << 40)
                             | ((unsigned long long)s0 << 60)
                             | ((unsigned long long)s1 << 61)
                             | ((unsigned long long)s2 << 62)
                             | ((unsigned long long)act << 63);
        gpack[f] = g;
        if (act) {
            atomicAdd(&hist[v0 >> BIN_BITS], 1u);
            atomicAdd(&hist[v1 >> BIN_BITS], 1u);
            atomicAdd(&hist[v2 >> BIN_BITS], 1u);
        }
    }
    __syncthreads();

    {
        const int t = threadIdx.x, lane = t & 63, wid = t >> 6;
        unsigned int a0 = hist[4 * t], a1 = hist[4 * t + 1];
        unsigned int a2 = hist[4 * t + 2], a3 = hist[4 * t + 3];
        unsigned int tsum = a0 + a1 + a2 + a3;
        unsigned int x = tsum;
        #pragma unroll
        for (int off = 1; off < 64; off <<= 1) {
            unsigned int y = (unsigned int)__shfl_up((int)x, off);
            if (lane >= off) x += y;
        }
        if (lane == 63) wsum[wid] = x;
        __syncthreads();
        unsigned int wbase = 0;
        for (int w = 0; w < wid; ++w) wbase += wsum[w];
        unsigned int e0x = wbase + x - tsum;
        unsigned int e1x = e0x + a0, e2x = e1x + a1, e3x = e2x + a2;
        cur[4 * t] = e0x; cur[4 * t + 1] = e1x; cur[4 * t + 2] = e2x; cur[4 * t + 3] = e3x;
        unsigned short* row = offs + (size_t)k * OROW;
        if (4 * t     <= NB) row[4 * t]     = (unsigned short)e0x;
        if (4 * t + 1 <= NB) row[4 * t + 1] = (unsigned short)e1x;
        if (4 * t + 2 <= NB) row[4 * t + 2] = (unsigned short)e2x;
        if (4 * t + 3 <= NB) row[4 * t + 3] = (unsigned short)e3x;
    }
    __syncthreads();

    const size_t rbase = (size_t)k * RSTRIDE;
    for (int j = threadIdx.x; j < n4; j += 256) {
        const int fb = f0 + 4 * j;
        ulonglong2 ga = *(const ulonglong2*)(gpack + fb);
        ulonglong2 gb = *(const ulonglong2*)(gpack + fb + 2);
        unsigned long long gq[4] = {ga.x, ga.y, gb.x, gb.y};
        #pragma unroll
        for (int q = 0; q < 4; ++q) {
            unsigned long long g = gq[q];
            if ((long long)g < 0) {
                unsigned int v0 = (unsigned int)(g & 0xFFFFFu);
                unsigned int v1 = (unsigned int)((g >> 20) & 0xFFFFFu);
                unsigned int v2 = (unsigned int)((g >> 40) & 0xFFFFFu);
                unsigned int sl0 = atomicAdd(&cur[v0 >> BIN_BITS], 1u);
                sorted[rbase + sl0] = (unsigned short)((v0 & (CH_SIZE - 1)) | ((unsigned int)((g >> 60) & 1u) << CH_BITS));
                unsigned int sl1 = atomicAdd(&cur[v1 >> BIN_BITS], 1u);
                sorted[rbase + sl1] = (unsigned short)((v1 & (CH_SIZE - 1)) | ((unsigned int)((g >> 61) & 1u) << CH_BITS));
                unsigned int sl2 = atomicAdd(&cur[v2 >> BIN_BITS], 1u);
                sorted[rbase + sl2] = (unsigned short)((v2 & (CH_SIZE - 1)) | ((unsigned int)((g >> 62) & 1u) << CH_BITS));
            }
        }
    }
    for (int i = 4 * n4 + threadIdx.x; i < n; i += 256) {
        unsigned long long g = gpack[f0 + i];
        if ((long long)g < 0) {
            unsigned int v0 = (unsigned int)(g & 0xFFFFFu);
            unsigned int v1 = (unsigned int)((g >> 20) & 0xFFFFFu);
            unsigned int v2 = (unsigned int)((g >> 40) & 0xFFFFFu);
            unsigned int sl0 = atomicAdd(&cur[v0 >> BIN_BITS], 1u);
            sorted[rbase + sl0] = (unsigned short)((v0 & (CH_SIZE - 1)) | ((unsigned int)((g >> 60) & 1u) << CH_BITS));
            unsigned int sl1 = atomicAdd(&cur[v1 >> BIN_BITS], 1u);
            sorted[rbase + sl1] = (unsigned short)((v1 & (CH_SIZE - 1)) | ((unsigned int)((g >> 61) & 1u) << CH_BITS));
            unsigned int sl2 = atomicAdd(&cur[v2 >> BIN_BITS], 1u);
            sorted[rbase + sl2] = (unsigned short)((v2 & (CH_SIZE - 1)) | ((unsigned int)((g >> 62) & 1u) << CH_BITS));
        }
    }
}

__global__ __launch_bounds__(1024) void k_accum(
    const unsigned short* __restrict__ offs_T,
    const unsigned short* __restrict__ sorted,
    const float* __restrict__ avars,
    unsigned int* __restrict__ packed,
    unsigned long long* __restrict__ avm,
    unsigned long long* __restrict__ svm,
    unsigned char* __restrict__ sgrp)
{
    __shared__ unsigned int acc[CH_SIZE];
    __shared__ unsigned short row0[SBLK];
    __shared__ unsigned short row1[SBLK];
    const int c = blockIdx.x;
    const int r0 = 4 * c;
    const int r1 = (4 * c + 4 < NB) ? (4 * c + 4) : NB;
    for (int i = threadIdx.x; i < CH_SIZE; i += 1024) acc[i] = 0u;
    for (int i = threadIdx.x; i < SBLK; i += 1024) {
        row0[i] = offs_T[(size_t)r0 * SBLK + i];
        row1[i] = offs_T[(size_t)r1 * SBLK + i];
    }
    __syncthreads();
    for (int k = threadIdx.x; k < SBLK; k += 1024) {
        const int s0 = row0[k], s1 = row1[k];
        const unsigned short* seg = sorted + (size_t)k * RSTRIDE;
        for (int e = s0; e < s1; ++e) {
            unsigned int p = seg[e];
            atomicAdd(&acc[p & (CH_SIZE - 1)], 0x10000u | (p >> CH_BITS));
        }
    }
    __syncthreads();
    const int vbase = c << CH_BITS;
    for (int i = threadIdx.x; i < CH_SIZE; i += 1024) {
        int v = vbase + i;
        bool valid = v < Vn;
        unsigned int p = valid ? acc[i] : 0u;
        bool av = valid && (avars[v] != 0.0f);
        unsigned int cnt = p >> 16, pos = p & 0xFFFFu;
        bool sv = av && (pos == 0u || pos == cnt);
        unsigned long long avb = __ballot(av);
        unsigned long long svb = __ballot(sv);
        if (valid) packed[v] = p;
        if ((threadIdx.x & 63) == 0) {
            avm[v >> 6] = avb;
            svm[v >> 6] = svb;
            sgrp[v >> 6] = (svb != 0ull) ? 1 : 0;
        }
    }
}

__global__ void k_zero_tmp(unsigned int* __restrict__ tmp, unsigned char* __restrict__ tgrp) {
    int v = blockIdx.x * blockDim.x + threadIdx.x;
    if (v < Vn) tmp[v] = 0u;
    if (v < AVW) tgrp[v] = 0;
}

__device__ __forceinline__ void fire_one(unsigned long long g, int f,
                                         unsigned long long* __restrict__ gpack,
                                         const unsigned int* __restrict__ svm32,
                                         const unsigned char* __restrict__ sgrp,
                                         unsigned int* __restrict__ tmp,
                                         unsigned char* __restrict__ tgrp)
{
    if ((long long)g >= 0) return;
    unsigned int v0 = (unsigned int)(g & 0xFFFFFu);
    unsigned int v1 = (unsigned int)((g >> 20) & 0xFFFFFu);
    unsigned int v2 = (unsigned int)((g >> 40) & 0xFFFFFu);
    if (!(sgrp[v0 >> 6] | sgrp[v1 >> 6] | sgrp[v2 >> 6])) return;
    unsigned int hit = ((svm32[v0 >> 5] >> (v0 & 31u)) |
                        (svm32[v1 >> 5] >> (v1 & 31u)) |
                        (svm32[v2 >> 5] >> (v2 & 31u))) & 1u;
    if (!hit) return;
    gpack[f] = g & ~(1ull << 63);
    atomicAdd(&tmp[v0], 0x10000u | (unsigned int)((g >> 60) & 1u));
    atomicAdd(&tmp[v1], 0x10000u | (unsigned int)((g >> 61) & 1u));
    atomicAdd(&tmp[v2], 0x10000u | (unsigned int)((g >> 62) & 1u));
    tgrp[v0 >> 6] = 1; tgrp[v1 >> 6] = 1; tgrp[v2 >> 6] = 1;
}

__global__ void k_funcs(unsigned long long* __restrict__ gpack,
                        const unsigned int* __restrict__ svm32,
                        const unsigned char* __restrict__ sgrp,
                        unsigned int* __restrict__ tmp,
                        unsigned char* __restrict__ tgrp)
{
    int gid = blockIdx.x * blockDim.x + threadIdx.x;
    int f = 2 * gid;
    if (f >= Fn) return;
    ulonglong2 g2 = *(const ulonglong2*)(gpack + f);
    fire_one(g2.x, f,     gpack, svm32, sgrp, tmp, tgrp);
    fire_one(g2.y, f + 1, gpack, svm32, sgrp, tmp, tgrp);
}

__global__ void k_update(unsigned int* __restrict__ packed,
                         unsigned int* __restrict__ tmp,
                         unsigned long long* __restrict__ avm,
                         unsigned long long* __restrict__ svm,
                         unsigned char* __restrict__ sgrp,
                         unsigned char* __restrict__ tgrp,
                         float* __restrict__ deg, int write_deg)
{
    int v = blockIdx.x * blockDim.x + threadIdx.x;
    int lane = threadIdx.x & 63;
    bool valid = v < Vn;
    unsigned long long avw = 0ull, svw = 0ull;
    unsigned char tg = 0;
    if (valid) {
        avw = avm[v >> 6]; svw = svm[v >> 6];
        tg = tgrp[v >> 6];
    }
    bool av_old = valid && ((avw >> lane) & 1ull);
    bool sv     = valid && ((svw >> lane) & 1ull);
    bool av_new = av_old && !sv;
    unsigned int p = 0u;
    if (valid) {
        p = packed[v];
        if (tg) {
            unsigned int tp = tmp[v];
            if (tp != 0u) {
                if (av_old) { p -= tp; packed[v] = p; }
                tmp[v] = 0u;
            }
        }
    }
    unsigned int c = p >> 16, pos = p & 0xFFFFu;
    bool nsv = av_new && (pos == 0u || pos == c);
    unsigned long long nsvb = __ballot(nsv);
    if (lane == 0 && valid) {
        svm[v >> 6] = nsvb;
        avm[v >> 6] = avw & ~svw;
        sgrp[v >> 6] = (nsvb != 0ull) ? 1 : 0;
        if (tg) tgrp[v >> 6] = 0;
    }
    if (write_deg && valid) deg[v] = (float)c;
}

// ======================= launcher =======================
extern "C" void kernel_launch(void* const* d_in, const int* in_sizes, int n_in,
                              void* d_out, int out_size, void* d_ws, size_t ws_size,
                              hipStream_t stream) {
    const int*   graph_map        = (const int*)d_in[0];
    const float* edge_feature     = (const float*)d_in[1];
    const float* active_variables = (const float*)d_in[2];
    const float* active_functions = (const float*)d_in[3];
    const int* vidx = graph_map;
    float* deg = (float*)d_out;
    char* ws = (char*)d_ws;

    const int BS = 256;
    const int gV = (Vn + BS - 1) / BS;
    const int gF = (Fn + BS - 1) / BS;

    // ---- CSR-path workspace requirement (identical to R12's proven NEED) ----
    const size_t szA   = 4ull * SBLK * RSTRIDE;       // u32 regions (alias frontB/touched after build)
    const size_t szOfs = 2ull * SBLK * OROW;          // offs (row_start aliases after transpose)
    const size_t szOfT = 2ull * SBLK * OROW;          // offs_T (eclaim aliases after build)
    const size_t szC   = 4ull * NCH * CH_SIZE;        // packed (padded)
    const size_t szCsr = 4ull * NB * CAP_BIN;         // csr (gpack staging aliases pre-build)
    const size_t szF   = 1ull * NCH * CH_SIZE;        // cnt8
    const size_t szFep = 4ull * Vn;
    const size_t szAv8 = 1ull * NCH * CH_SIZE;
    const size_t szFrA = 4ull * Vn;
    const size_t szFm  = 4ull * ((FWORDS + 127) & ~127);
    const size_t szMisc = 65536;
    const size_t NEED = szA + szOfs + szOfT + szC + szCsr + szF + szFep + szAv8 + szFrA + szFm + szMisc;

    if (ws_size >= NEED) {
        // ================= CSR / frontier path =================
        size_t off = 0;
        unsigned int* regions32 = (unsigned int*)(ws + off); off += szA;
        unsigned int* frontB  = (unsigned int*)((char*)regions32);                // 4 MB (dead sorted)
        unsigned int* touched = (unsigned int*)((char*)regions32 + 4ull * Vn);    // 32 MB (dead sorted)
        unsigned short* offs   = (unsigned short*)(ws + off); off += szOfs;
        unsigned int* row_start = (unsigned int*)offs;        // alias (offs dead after transpose)
        unsigned short* offs_T = (unsigned short*)(ws + off); off += szOfT;
        unsigned int* eclaim = (unsigned int*)offs_T;         // alias (dead after build; zeroed in funcs_0)
        unsigned int* packed   = (unsigned int*)(ws + off); off += szC;
        unsigned int* csr      = (unsigned int*)(ws + off); off += szCsr;
        unsigned long long* gpack = (unsigned long long*)csr; // staging alias (dead before kc_build)
        unsigned char* cnt8     = (unsigned char*)(ws + off); off += szF;
        unsigned int* fep       = (unsigned int*)(ws + off); off += szFep;
        unsigned char* av8      = (unsigned char*)(ws + off); off += szAv8;
        unsigned int* frontA    = (unsigned int*)(ws + off); off += szFrA;
        unsigned int* fmask     = (unsigned int*)(ws + off); off += szFm;
        unsigned int* counters  = (unsigned int*)(ws + off); off += 4096;

        kc_init<<<gF, BS, 0, stream>>>(active_functions, fmask, fep, counters);
        kc_pack_sort<<<SBLK, 256, 0, stream>>>(vidx, edge_feature, active_functions, gpack, offs, regions32);
        k_transpose<<<dim3(OROW / 64, SBLK / 64), 256, 0, stream>>>(offs, offs_T);
        kc_build<<<248, 1024, 0, stream>>>(offs_T, regions32, active_variables, packed,
                                           av8, cnt8, row_start, csr, frontA, counters, fep);
        for (int t = 0; t < Tn; ++t) {
            const unsigned int* fcur = (t & 1) ? frontB : frontA;
            unsigned int* fnext = (t & 1) ? frontA : frontB;
            kc_funcs<<<256, 256, 0, stream>>>(csr, row_start, cnt8, fmask, vidx, edge_feature,
                                              packed, av8, touched, counters, fcur, eclaim, t);
            if (t < Tn - 1)
                kc_update<<<256, 256, 0, stream>>>(packed, av8, fep, eclaim, touched,
                                                   fcur, fnext, counters, t);
        }
        kc_out<<<gV, BS, 0, stream>>>(packed, deg);
    } else {
        // ================= R8 fallback path =================
        size_t off = 0;
        unsigned long long* gpack = (unsigned long long*)(ws + off); off += 8ull * Fn;
        unsigned int* packed      = (unsigned int*)(ws + off);       off += 4ull * Vn;
        unsigned long long* avm   = (unsigned long long*)(ws + off); off += 8ull * AVW;
        unsigned long long* svm   = (unsigned long long*)(ws + off); off += 8ull * AVW;
        unsigned char* sgrp       = (unsigned char*)(ws + off);      off += (size_t)((AVW + 255) & ~255);
        unsigned char* tgrp       = (unsigned char*)(ws + off);      off += (size_t)((AVW + 255) & ~255);
        unsigned short* offs      = (unsigned short*)(ws + off);     off += 2ull * SBLK * OROW;
        unsigned short* offs_T    = (unsigned short*)(ws + off);     off += 2ull * SBLK * OROW;
        unsigned short* sorted    = (unsigned short*)(ws + off);     off += 2ull * SBLK * RSTRIDE;
        unsigned int* tmp = (unsigned int*)sorted;

        const int gF2 = (Fn / 2 + BS - 1) / BS;
        k_pack_sort<<<SBLK, 256, 0, stream>>>(vidx, edge_feature, active_functions, gpack, offs, sorted);
        k_transpose<<<dim3(OROW / 64, SBLK / 64), 256, 0, stream>>>(offs, offs_T);
        k_accum<<<NCH, 1024, 0, stream>>>(offs_T, sorted, active_variables, packed, avm, svm, sgrp);
        k_zero_tmp<<<gV, BS, 0, stream>>>(tmp, tgrp);
        for (int t = 0; t < Tn; ++t) {
            k_funcs<<<gF2, BS, 0, stream>>>(gpack, (const unsigned int*)svm, sgrp, tmp, tgrp);
            k_update<<<gV, BS, 0, stream>>>(packed, tmp, avm, svm, sgrp, tgrp, deg, (t == Tn - 1) ? 1 : 0);
        }
    }
}